// Round 3
// baseline (1062.485 us; speedup 1.0000x reference)
//
#include <hip/hip_runtime.h>
#include <math.h>

// Problem constants
#define NB 8
#define NT 512           // N_FRAMES
#define NROWS 4096       // NB*NT
#define CI 512           // C_INT
#define DM 1536          // D_MLP
#define CCON 192
#define CSPK 256
#define NW 1024          // N_WINDOW
#define FS 960           // FRAME_SIZE
#define LTOT 491520      // NT*FS
#define CONVW 1984       // FS+NW

typedef __bf16 bf16x8 __attribute__((ext_vector_type(8)));
typedef float f32x4 __attribute__((ext_vector_type(4)));
typedef unsigned short ushort;

__device__ __forceinline__ ushort f2bf(float x) {
    union { float f; unsigned u; } v; v.f = x;
    unsigned r = v.u + 0x7fff + ((v.u >> 16) & 1);
    return (ushort)(r >> 16);
}

#define ASYNC_COPY16(g, l) __builtin_amdgcn_global_load_lds( \
    (const __attribute__((address_space(1))) void*)(g), \
    (__attribute__((address_space(3))) void*)(l), 16, 0, 0)

// ---------------- weight fp32 -> bf16 (elementwise, 4/thread)
__global__ void cvt_bf16(const float* __restrict__ in, ushort* __restrict__ out, int n4) {
    int i = blockIdx.x * 256 + threadIdx.x;
    if (i < n4) {
        float4 v = ((const float4*)in)[i];
        ushort4 o; o.x = f2bf(v.x); o.y = f2bf(v.y); o.z = f2bf(v.z); o.w = f2bf(v.w);
        ((ushort4*)out)[i] = o;
    }
}

// ---------------- w_out (NW, CI, 7) -> wk[k][n][c] bf16
__global__ void cvt_wout(const float* __restrict__ w, ushort* __restrict__ wk) {
    int n = blockIdx.x, tid = threadIdx.x;
    __shared__ ushort s[7][512];
#pragma unroll
    for (int h = 0; h < 2; ++h) {
        int c = tid + h * 256;
        const float* p = w + ((size_t)n * 512 + c) * 7;
#pragma unroll
        for (int k = 0; k < 7; ++k) s[k][c] = f2bf(p[k]);
    }
    __syncthreads();
#pragma unroll
    for (int k = 0; k < 7; ++k)
#pragma unroll
        for (int h = 0; h < 2; ++h) {
            int c = tid + h * 256;
            wk[((size_t)k * NW + n) * CI + c] = s[k][c];
        }
}

// ---------------- spk base
__global__ void spkbase_kernel(const float* __restrict__ spk, const float* __restrict__ w_spk,
                               const float* __restrict__ b_spk, const float* __restrict__ b_content,
                               const float* __restrict__ b_f0, const float* __restrict__ b_energy,
                               float* __restrict__ base) {
    int b = blockIdx.x, tid = threadIdx.x;
    __shared__ float s[CSPK];
    if (tid < CSPK) s[tid] = spk[b * CSPK + tid];
    __syncthreads();
    for (int o = tid; o < CI; o += 256) {
        float acc = 0.f;
        for (int c = 0; c < CSPK; ++c) acc = fmaf(w_spk[o * CSPK + c], s[c], acc);
        base[b * CI + o] = acc + b_spk[o] + b_content[o] + b_f0[o] + b_energy[o];
    }
}

// ---------------- content transpose: (B, 192, T) -> ct[(b*T+t)][c]
__global__ void transpose_content(const float* __restrict__ content, float* __restrict__ ct) {
    __shared__ float tile[32][33];
    int b = blockIdx.z, c0 = blockIdx.y * 32, t0 = blockIdx.x * 32;
    int x = threadIdx.x, y = threadIdx.y;
#pragma unroll
    for (int i = 0; i < 32; i += 8)
        tile[y + i][x] = content[((size_t)b * CCON + c0 + y + i) * NT + t0 + x];
    __syncthreads();
#pragma unroll
    for (int i = 0; i < 32; i += 8)
        ct[((size_t)b * NT + t0 + y + i) * CCON + c0 + x] = tile[x][y + i];
}

// ---------------- fp32 trunk GEMM (K=192, small)
#define BK 16
#define TILE 64
__global__ __launch_bounds__(256) void gemm_trunk(
    const float* __restrict__ A, const float* __restrict__ W, float* __restrict__ out,
    const float* __restrict__ base, const float* __restrict__ f0, const float* __restrict__ energy,
    const float* __restrict__ w_f0, const float* __restrict__ w_energy) {
    __shared__ float As[BK][TILE + 4];
    __shared__ float Ws[BK][TILE + 4];
    int tid = threadIdx.x;
    int tx = tid & 15, ty = tid >> 4;
    int m0 = blockIdx.x * TILE, n0 = blockIdx.y * TILE;
    int lr = tid >> 2, lq = tid & 3;
    const float* Ag = A + (size_t)(m0 + lr) * CCON + lq * 4;
    const float* Wg = W + (size_t)(n0 + lr) * CCON + lq * 4;
    float acc[4][4] = {};
    for (int k0 = 0; k0 < CCON; k0 += BK) {
        float4 av = *(const float4*)(Ag + k0);
        float4 wv = *(const float4*)(Wg + k0);
        As[lq * 4 + 0][lr] = av.x; As[lq * 4 + 1][lr] = av.y;
        As[lq * 4 + 2][lr] = av.z; As[lq * 4 + 3][lr] = av.w;
        Ws[lq * 4 + 0][lr] = wv.x; Ws[lq * 4 + 1][lr] = wv.y;
        Ws[lq * 4 + 2][lr] = wv.z; Ws[lq * 4 + 3][lr] = wv.w;
        __syncthreads();
#pragma unroll
        for (int kk = 0; kk < BK; ++kk) {
            float4 a4 = *(const float4*)&As[kk][ty * 4];
            float4 b4 = *(const float4*)&Ws[kk][tx * 4];
            float aa[4] = {a4.x, a4.y, a4.z, a4.w};
            float bb[4] = {b4.x, b4.y, b4.z, b4.w};
#pragma unroll
            for (int i = 0; i < 4; ++i)
#pragma unroll
                for (int j = 0; j < 4; ++j) acc[i][j] = fmaf(aa[i], bb[j], acc[i][j]);
        }
        __syncthreads();
    }
#pragma unroll
    for (int i = 0; i < 4; ++i) {
        int m = m0 + ty * 4 + i;
        float fv = logf(fmaxf(f0[m], 0.f) + 1e-6f);
        float ev = energy[m];
        int b = m >> 9;
        float4 o4;
        float res[4];
#pragma unroll
        for (int j = 0; j < 4; ++j) {
            int o = n0 + tx * 4 + j;
            res[j] = acc[i][j] + base[(b << 9) + o] + w_f0[o] * fv + w_energy[o] * ev;
        }
        o4.x = res[0]; o4.y = res[1]; o4.z = res[2]; o4.w = res[3];
        *(float4*)(out + (size_t)m * CI + n0 + tx * 4) = o4;
    }
}

// ---------------- bf16 MFMA GEMM: out[m][n] = epi( sum_k A[m][k] * W[n][k] )
// MODE 1: +bias, gelu, bf16 out. MODE 2: +bias +residual(fp32), fp32 out.
template <int MODE, int TM, int TN>
__global__ __launch_bounds__(256) void gemm_mfma(
    const ushort* __restrict__ A, const ushort* __restrict__ W,
    const float* __restrict__ bias, void* __restrict__ outp,
    const float* __restrict__ res, int K, int NC) {
    constexpr int MI = TM / 32, NI = TN / 32;
    __shared__ ushort As[TM * 32];
    __shared__ ushort Bs[TN * 32];
    int tid = threadIdx.x;
    int wave = tid >> 6, lane = tid & 63;
    int m0 = blockIdx.x * TM, n0 = blockIdx.y * TN;
    int srow = lane >> 2, schunk = lane & 3;
    const ushort* Ag = A + (size_t)(m0 + wave * (TM / 4) + srow) * K + schunk * 8;
    const ushort* Wg = W + (size_t)(n0 + wave * (TN / 4) + srow) * K + schunk * 8;
    ushort* Al = &As[(wave * (TM / 4)) * 32];
    ushort* Bl = &Bs[(wave * (TN / 4)) * 32];
    int lm = lane & 15, kq = lane >> 4;
    int wm = wave & 1, wn = wave >> 1;
    f32x4 acc[MI][NI];
#pragma unroll
    for (int i = 0; i < MI; ++i)
#pragma unroll
        for (int j = 0; j < NI; ++j) acc[i][j] = (f32x4)0.f;

    for (int k0 = 0; k0 < K; k0 += 32) {
#pragma unroll
        for (int i = 0; i < TM / 64; ++i)
            ASYNC_COPY16(Ag + k0 + (size_t)i * 16 * K, Al + i * 16 * 32);
#pragma unroll
        for (int i = 0; i < TN / 64; ++i)
            ASYNC_COPY16(Wg + k0 + (size_t)i * 16 * K, Bl + i * 16 * 32);
        __syncthreads();
        bf16x8 af[MI], bf[NI];
#pragma unroll
        for (int i = 0; i < MI; ++i)
            af[i] = *(const bf16x8*)&As[(wm * (TM / 2) + i * 16 + lm) * 32 + kq * 8];
#pragma unroll
        for (int j = 0; j < NI; ++j)
            bf[j] = *(const bf16x8*)&Bs[(wn * (TN / 2) + j * 16 + lm) * 32 + kq * 8];
#pragma unroll
        for (int i = 0; i < MI; ++i)
#pragma unroll
            for (int j = 0; j < NI; ++j)
                acc[i][j] = __builtin_amdgcn_mfma_f32_16x16x32_bf16(af[i], bf[j], acc[i][j], 0, 0, 0);
        __syncthreads();
    }
#pragma unroll
    for (int i = 0; i < MI; ++i)
#pragma unroll
        for (int j = 0; j < NI; ++j) {
            int col = n0 + wn * (TN / 2) + j * 16 + lm;
            float bv = bias[col];
#pragma unroll
            for (int r = 0; r < 4; ++r) {
                int row = m0 + wm * (TM / 2) + i * 16 + kq * 4 + r;
                float v = acc[i][j][r] + bv;
                if (MODE == 1) {
                    v = 0.5f * v * (1.f + erff(v * 0.70710678118654752f));
                    ((ushort*)outp)[(size_t)row * NC + col] = f2bf(v);
                } else {
                    v += res[(size_t)row * NC + col];
                    ((float*)outp)[(size_t)row * NC + col] = v;
                }
            }
        }
}

// ---------------- head: filt[m][n] = sum_{k,c} h[b, clamp(t+k-3)][c] * wk[k][n][c] + b_out[n]
__global__ __launch_bounds__(256) void head_mfma(
    const ushort* __restrict__ H, const ushort* __restrict__ WK,
    const float* __restrict__ bias, float* __restrict__ out) {
    constexpr int TM = 128, TN = 128, MI = 4, NI = 4;
    __shared__ ushort As[TM * 32];
    __shared__ ushort Bs[TN * 32];
    int tid = threadIdx.x;
    int wave = tid >> 6, lane = tid & 63;
    int m0 = blockIdx.x * TM, n0 = blockIdx.y * TN;
    int b = m0 >> 9, tbase = m0 & (NT - 1);
    int srow = lane >> 2, schunk = lane & 3;
    ushort* Al = &As[(wave * 32) * 32];
    ushort* Bl = &Bs[(wave * 32) * 32];
    int lm = lane & 15, kq = lane >> 4;
    int wm = wave & 1, wn = wave >> 1;
    f32x4 acc[MI][NI];
#pragma unroll
    for (int i = 0; i < MI; ++i)
#pragma unroll
        for (int j = 0; j < NI; ++j) acc[i][j] = (f32x4)0.f;

    for (int k = 0; k < 7; ++k) {
        const ushort* ag[2];
#pragma unroll
        for (int i = 0; i < 2; ++i) {
            int t = tbase + wave * 32 + i * 16 + srow + k - 3;
            t = min(max(t, 0), NT - 1);
            ag[i] = H + ((size_t)(b << 9) + t) * CI + schunk * 8;
        }
        const ushort* wg = WK + ((size_t)k * NW + n0 + wave * 32 + srow) * CI + schunk * 8;
        for (int c0 = 0; c0 < CI; c0 += 32) {
#pragma unroll
            for (int i = 0; i < 2; ++i)
                ASYNC_COPY16(ag[i] + c0, Al + i * 16 * 32);
#pragma unroll
            for (int i = 0; i < 2; ++i)
                ASYNC_COPY16(wg + c0 + (size_t)i * 16 * CI, Bl + i * 16 * 32);
            __syncthreads();
            bf16x8 af[MI], bf[NI];
#pragma unroll
            for (int i = 0; i < MI; ++i)
                af[i] = *(const bf16x8*)&As[(wm * 64 + i * 16 + lm) * 32 + kq * 8];
#pragma unroll
            for (int j = 0; j < NI; ++j)
                bf[j] = *(const bf16x8*)&Bs[(wn * 64 + j * 16 + lm) * 32 + kq * 8];
#pragma unroll
            for (int i = 0; i < MI; ++i)
#pragma unroll
                for (int j = 0; j < NI; ++j)
                    acc[i][j] = __builtin_amdgcn_mfma_f32_16x16x32_bf16(af[i], bf[j], acc[i][j], 0, 0, 0);
            __syncthreads();
        }
    }
#pragma unroll
    for (int i = 0; i < MI; ++i)
#pragma unroll
        for (int j = 0; j < NI; ++j) {
            int col = n0 + wn * 64 + j * 16 + lm;
            float bv = bias[col];
#pragma unroll
            for (int r = 0; r < 4; ++r) {
                int row = m0 + wm * 64 + i * 16 + kq * 4 + r;
                out[(size_t)row * NW + col] = acc[i][j][r] + bv;
            }
        }
}

// ---------------- dw conv + LN (wave-per-row, channels strided by 64)
template <bool DW>
__global__ __launch_bounds__(256) void dwln_kernel(const float* __restrict__ X, ushort* __restrict__ H,
                                                   const float* __restrict__ dw_w,
                                                   const float* __restrict__ dw_b,
                                                   const float* __restrict__ g,
                                                   const float* __restrict__ bb) {
    __shared__ float wt[7][512];
    int tid = threadIdx.x;
    if (DW) {
        for (int i = tid; i < 3584; i += 256) {
            int c = i / 7, k = i - c * 7;
            wt[k][c] = dw_w[i];
        }
        __syncthreads();
    }
    int wid = tid >> 6, lane = tid & 63;
    int n = blockIdx.x * 4 + wid;
    int b = n >> 9, t = n & (NT - 1);
    float v[8];
    if (DW) {
#pragma unroll
        for (int i = 0; i < 8; ++i) v[i] = dw_b[lane + 64 * i];
#pragma unroll
        for (int k = 0; k < 7; ++k) {
            int tt = t + k - 3;
            if (tt >= 0 && tt < NT) {
                const float* xr = X + ((size_t)(b << 9) + tt) * CI + lane;
#pragma unroll
                for (int i = 0; i < 8; ++i)
                    v[i] = fmaf(wt[k][lane + 64 * i], xr[64 * i], v[i]);
            }
        }
    } else {
        const float* xr = X + (size_t)n * CI + lane;
#pragma unroll
        for (int i = 0; i < 8; ++i) v[i] = xr[64 * i];
    }
    float s1 = 0.f, s2 = 0.f;
#pragma unroll
    for (int i = 0; i < 8; ++i) { s1 += v[i]; s2 = fmaf(v[i], v[i], s2); }
#pragma unroll
    for (int off = 1; off < 64; off <<= 1) {
        s1 += __shfl_xor(s1, off);
        s2 += __shfl_xor(s2, off);
    }
    float mean = s1 * (1.f / CI);
    float rs = rsqrtf(s2 * (1.f / CI) - mean * mean + 1e-6f);
    ushort* hr = H + (size_t)n * CI + lane;
#pragma unroll
    for (int i = 0; i < 8; ++i) {
        int c = lane + 64 * i;
        hr[64 * i] = f2bf((v[i] - mean) * rs * g[c] + bb[c]);
    }
}

// ---------------- per-frame FIR: conv[bg][u] = sum_j s[j] * P[1988 - u + j]
// thread owns 8 consecutive u; j unrolled x4 via ds_read_b128; rolling 11-tap window
__global__ __launch_bounds__(256) void fir_kernel(const float* __restrict__ source,
                                                  const float* __restrict__ filt,
                                                  float* __restrict__ conv) {
    __shared__ float P[2948];     // tap k at P[k+964], zeros elsewhere
    __shared__ float s_src[FS];
    int tid = threadIdx.x;
    int bg = blockIdx.x;
    int b = bg >> 9, g = bg & (NT - 1);
    for (int i = tid; i < 2948; i += 256) P[i] = 0.f;
    __syncthreads();
    {
        float4 fv = ((const float4*)(filt + (size_t)bg * NW))[tid];
        *(float4*)&P[964 + tid * 4] = fv;
    }
    if (tid < 240) {
        float4 sv = ((const float4*)(source + (size_t)b * LTOT + g * FS))[tid];
        *(float4*)&s_src[tid * 4] = sv;
    }
    __syncthreads();
    if (tid < 248) {
        int u0 = tid * 8;
        int pb = 1988 - u0;                 // pb % 4 == 0 -> all quads 16B-aligned
        float a[8] = {0.f, 0.f, 0.f, 0.f, 0.f, 0.f, 0.f, 0.f};
        float w[11];
        float4 q;
        q = *(const float4*)&P[pb - 8];
        w[0] = q.y; w[1] = q.z; w[2] = q.w;
        q = *(const float4*)&P[pb - 4];
        w[3] = q.x; w[4] = q.y; w[5] = q.z; w[6] = q.w;
#pragma unroll 4
        for (int J = 0; J < 240; ++J) {
            float4 pc = *(const float4*)&P[pb + J * 4];
            float4 s4 = *(const float4*)&s_src[J * 4];
            w[7] = pc.x; w[8] = pc.y; w[9] = pc.z; w[10] = pc.w;
            float sv;
            sv = s4.x;
#pragma unroll
            for (int d = 0; d < 8; ++d) a[d] = fmaf(sv, w[7 - d], a[d]);
            sv = s4.y;
#pragma unroll
            for (int d = 0; d < 8; ++d) a[d] = fmaf(sv, w[8 - d], a[d]);
            sv = s4.z;
#pragma unroll
            for (int d = 0; d < 8; ++d) a[d] = fmaf(sv, w[9 - d], a[d]);
            sv = s4.w;
#pragma unroll
            for (int d = 0; d < 8; ++d) a[d] = fmaf(sv, w[10 - d], a[d]);
#pragma unroll
            for (int r = 0; r < 7; ++r) w[r] = w[r + 4];
        }
        float4 o;
        o.x = a[0]; o.y = a[1]; o.z = a[2]; o.w = a[3];
        *(float4*)(conv + (size_t)bg * CONVW + u0) = o;
        o.x = a[4]; o.y = a[5]; o.z = a[6]; o.w = a[7];
        *(float4*)(conv + (size_t)bg * CONVW + u0 + 4) = o;
    }
}

// ---------------- overlap-add fold
__global__ void fold_kernel(const float* __restrict__ conv, float* __restrict__ out) {
    int b = blockIdx.y;
    int t = blockIdx.x * blockDim.x + threadIdx.x;
    float sum = 0.f;
    int G = (t - 1) / 960;
#pragma unroll
    for (int r = 0; r < 3; ++r) {
        int g = G - r;
        if (g >= 0) {
            int u = t - 960 * g;
            if (u < CONVW) sum += conv[((size_t)(b * NT + g)) * CONVW + u];
        }
    }
    out[(size_t)b * LTOT + t] = sum;
}

extern "C" void kernel_launch(void* const* d_in, const int* in_sizes, int n_in,
                              void* d_out, int out_size, void* d_ws, size_t ws_size,
                              hipStream_t stream) {
    const float* content  = (const float*)d_in[0];
    const float* f0       = (const float*)d_in[1];
    const float* energy   = (const float*)d_in[2];
    const float* spk      = (const float*)d_in[3];
    const float* source   = (const float*)d_in[4];
    const float* w_content= (const float*)d_in[5];
    const float* b_content= (const float*)d_in[6];
    const float* w_spk    = (const float*)d_in[7];
    const float* b_spk    = (const float*)d_in[8];
    const float* w_f0     = (const float*)d_in[9];
    const float* b_f0     = (const float*)d_in[10];
    const float* w_energy = (const float*)d_in[11];
    const float* b_energy = (const float*)d_in[12];
    const float* dw_w     = (const float*)d_in[13];
    const float* dw_b     = (const float*)d_in[14];
    const float* ln_g     = (const float*)d_in[15];
    const float* ln_b     = (const float*)d_in[16];
    const float* pw1_w    = (const float*)d_in[17];
    const float* pw1_b    = (const float*)d_in[18];
    const float* pw2_w    = (const float*)d_in[19];
    const float* pw2_b    = (const float*)d_in[20];
    const float* out_ln_g = (const float*)d_in[21];
    const float* out_ln_b = (const float*)d_in[22];
    const float* w_out    = (const float*)d_in[23];
    const float* b_out    = (const float*)d_in[24];
    float* out = (float*)d_out;

    float* ws = (float*)d_ws;
    float*  x    = ws;                              // 2,097,152 f
    float*  base = ws + 2097152;                    // 4,096 f
    float*  ct   = ws + 2101248;                    // 786,432 f
    float*  filt = ws + 2887680;                    // 4,194,304 f
    ushort* h    = (ushort*)(ws + 7081984);         // 2,097,152 bf16
    ushort* pw1w = (ushort*)(ws + 8130560);         // 4,718,592 bf16
    ushort* pw2w = (ushort*)(ws + 10489856);        // 4,718,592 bf16
    ushort* wk   = (ushort*)(ws + 12849152);        // 3,670,016 bf16
    ushort* hmid = (ushort*)(ws + 14684160);        // 6,291,456 bf16
    float*  conv = ws + 8130560;                    // 8,126,464 f (after head_mfma done)

    cvt_bf16<<<4608, 256, 0, stream>>>(pw1_w, pw1w, 1179648);
    cvt_bf16<<<4608, 256, 0, stream>>>(pw2_w, pw2w, 1179648);
    cvt_wout<<<NW, 256, 0, stream>>>(w_out, wk);
    spkbase_kernel<<<NB, 256, 0, stream>>>(spk, w_spk, b_spk, b_content, b_f0, b_energy, base);
    transpose_content<<<dim3(16, 6, NB), dim3(32, 8), 0, stream>>>(content, ct);

    gemm_trunk<<<dim3(NROWS / TILE, CI / TILE), 256, 0, stream>>>(
        ct, w_content, x, base, f0, energy, w_f0, w_energy);

    for (int i = 0; i < 6; ++i) {
        dwln_kernel<true><<<NROWS / 4, 256, 0, stream>>>(x, h, dw_w + i * CI * 7, dw_b + i * CI,
                                                         ln_g + i * CI, ln_b + i * CI);
        gemm_mfma<1, 128, 128><<<dim3(NROWS / 128, DM / 128), 256, 0, stream>>>(
            h, pw1w + (size_t)i * DM * CI, pw1_b + i * DM, hmid, nullptr, CI, DM);
        gemm_mfma<2, 128, 64><<<dim3(NROWS / 128, CI / 64), 256, 0, stream>>>(
            hmid, pw2w + (size_t)i * CI * DM, pw2_b + i * CI, x, x, DM, CI);
    }

    dwln_kernel<false><<<NROWS / 4, 256, 0, stream>>>(x, h, nullptr, nullptr, out_ln_g, out_ln_b);
    head_mfma<<<dim3(NROWS / 128, NW / 128), 256, 0, stream>>>(h, wk, b_out, filt);
    fir_kernel<<<NROWS, 256, 0, stream>>>(source, filt, conv);
    fold_kernel<<<dim3(LTOT / 256, NB), 256, 0, stream>>>(conv, out);
}

// Round 4
// 687.101 us; speedup vs baseline: 1.5463x; 1.5463x over previous
//
#include <hip/hip_runtime.h>
#include <math.h>

// Problem constants
#define NB 8
#define NT 512           // N_FRAMES
#define NROWS 4096       // NB*NT
#define CI 512           // C_INT
#define DM 1536          // D_MLP
#define CCON 192
#define CSPK 256
#define NW 1024          // N_WINDOW
#define FS 960           // FRAME_SIZE
#define LTOT 491520      // NT*FS
#define CONVW 1984       // FS+NW

typedef __bf16 bf16x8 __attribute__((ext_vector_type(8)));
typedef float f32x4 __attribute__((ext_vector_type(4)));
typedef unsigned short ushort;

__device__ __forceinline__ ushort f2bf(float x) {
    union { float f; unsigned u; } v; v.f = x;
    unsigned r = v.u + 0x7fff + ((v.u >> 16) & 1);
    return (ushort)(r >> 16);
}

#define ASYNC_COPY16(g, l) __builtin_amdgcn_global_load_lds( \
    (const __attribute__((address_space(1))) void*)(g), \
    (__attribute__((address_space(3))) void*)(l), 16, 0, 0)

// ---------------- weight fp32 -> bf16 (elementwise, 4/thread)
__global__ void cvt_bf16(const float* __restrict__ in, ushort* __restrict__ out, int n4) {
    int i = blockIdx.x * 256 + threadIdx.x;
    if (i < n4) {
        float4 v = ((const float4*)in)[i];
        ushort4 o; o.x = f2bf(v.x); o.y = f2bf(v.y); o.z = f2bf(v.z); o.w = f2bf(v.w);
        ((ushort4*)out)[i] = o;
    }
}

// ---------------- w_out (NW, CI, 7) -> wk[k][n][c] bf16
__global__ void cvt_wout(const float* __restrict__ w, ushort* __restrict__ wk) {
    int n = blockIdx.x, tid = threadIdx.x;
    __shared__ ushort s[7][512];
#pragma unroll
    for (int h = 0; h < 2; ++h) {
        int c = tid + h * 256;
        const float* p = w + ((size_t)n * 512 + c) * 7;
#pragma unroll
        for (int k = 0; k < 7; ++k) s[k][c] = f2bf(p[k]);
    }
    __syncthreads();
#pragma unroll
    for (int k = 0; k < 7; ++k)
#pragma unroll
        for (int h = 0; h < 2; ++h) {
            int c = tid + h * 256;
            wk[((size_t)k * NW + n) * CI + c] = s[k][c];
        }
}

// ---------------- spk base
__global__ void spkbase_kernel(const float* __restrict__ spk, const float* __restrict__ w_spk,
                               const float* __restrict__ b_spk, const float* __restrict__ b_content,
                               const float* __restrict__ b_f0, const float* __restrict__ b_energy,
                               float* __restrict__ base) {
    int b = blockIdx.x, tid = threadIdx.x;
    __shared__ float s[CSPK];
    if (tid < CSPK) s[tid] = spk[b * CSPK + tid];
    __syncthreads();
    for (int o = tid; o < CI; o += 256) {
        float acc = 0.f;
        for (int c = 0; c < CSPK; ++c) acc = fmaf(w_spk[o * CSPK + c], s[c], acc);
        base[b * CI + o] = acc + b_spk[o] + b_content[o] + b_f0[o] + b_energy[o];
    }
}

// ---------------- content transpose: (B, 192, T) -> ct[(b*T+t)][c]
__global__ void transpose_content(const float* __restrict__ content, float* __restrict__ ct) {
    __shared__ float tile[32][33];
    int b = blockIdx.z, c0 = blockIdx.y * 32, t0 = blockIdx.x * 32;
    int x = threadIdx.x, y = threadIdx.y;
#pragma unroll
    for (int i = 0; i < 32; i += 8)
        tile[y + i][x] = content[((size_t)b * CCON + c0 + y + i) * NT + t0 + x];
    __syncthreads();
#pragma unroll
    for (int i = 0; i < 32; i += 8)
        ct[((size_t)b * NT + t0 + y + i) * CCON + c0 + x] = tile[x][y + i];
}

// ---------------- fp32 trunk GEMM (K=192, small)
#define BK 16
#define TILE 64
__global__ __launch_bounds__(256) void gemm_trunk(
    const float* __restrict__ A, const float* __restrict__ W, float* __restrict__ out,
    const float* __restrict__ base, const float* __restrict__ f0, const float* __restrict__ energy,
    const float* __restrict__ w_f0, const float* __restrict__ w_energy) {
    __shared__ float As[BK][TILE + 4];
    __shared__ float Ws[BK][TILE + 4];
    int tid = threadIdx.x;
    int tx = tid & 15, ty = tid >> 4;
    int m0 = blockIdx.x * TILE, n0 = blockIdx.y * TILE;
    int lr = tid >> 2, lq = tid & 3;
    const float* Ag = A + (size_t)(m0 + lr) * CCON + lq * 4;
    const float* Wg = W + (size_t)(n0 + lr) * CCON + lq * 4;
    float acc[4][4] = {};
    for (int k0 = 0; k0 < CCON; k0 += BK) {
        float4 av = *(const float4*)(Ag + k0);
        float4 wv = *(const float4*)(Wg + k0);
        As[lq * 4 + 0][lr] = av.x; As[lq * 4 + 1][lr] = av.y;
        As[lq * 4 + 2][lr] = av.z; As[lq * 4 + 3][lr] = av.w;
        Ws[lq * 4 + 0][lr] = wv.x; Ws[lq * 4 + 1][lr] = wv.y;
        Ws[lq * 4 + 2][lr] = wv.z; Ws[lq * 4 + 3][lr] = wv.w;
        __syncthreads();
#pragma unroll
        for (int kk = 0; kk < BK; ++kk) {
            float4 a4 = *(const float4*)&As[kk][ty * 4];
            float4 b4 = *(const float4*)&Ws[kk][tx * 4];
            float aa[4] = {a4.x, a4.y, a4.z, a4.w};
            float bb[4] = {b4.x, b4.y, b4.z, b4.w};
#pragma unroll
            for (int i = 0; i < 4; ++i)
#pragma unroll
                for (int j = 0; j < 4; ++j) acc[i][j] = fmaf(aa[i], bb[j], acc[i][j]);
        }
        __syncthreads();
    }
#pragma unroll
    for (int i = 0; i < 4; ++i) {
        int m = m0 + ty * 4 + i;
        float fv = logf(fmaxf(f0[m], 0.f) + 1e-6f);
        float ev = energy[m];
        int b = m >> 9;
        float4 o4;
        float res[4];
#pragma unroll
        for (int j = 0; j < 4; ++j) {
            int o = n0 + tx * 4 + j;
            res[j] = acc[i][j] + base[(b << 9) + o] + w_f0[o] * fv + w_energy[o] * ev;
        }
        o4.x = res[0]; o4.y = res[1]; o4.z = res[2]; o4.w = res[3];
        *(float4*)(out + (size_t)m * CI + n0 + tx * 4) = o4;
    }
}

// ---------------- bf16 MFMA GEMM: out[m][n] = epi( sum_k A[m][k] * W[n][k] )
// MODE 1: +bias, gelu, bf16 out. MODE 2: +bias +residual(fp32), fp32 out.
template <int MODE, int TM, int TN>
__global__ __launch_bounds__(256) void gemm_mfma(
    const ushort* __restrict__ A, const ushort* __restrict__ W,
    const float* __restrict__ bias, void* __restrict__ outp,
    const float* __restrict__ res, int K, int NC) {
    constexpr int MI = TM / 32, NI = TN / 32;
    __shared__ ushort As[TM * 32];
    __shared__ ushort Bs[TN * 32];
    int tid = threadIdx.x;
    int wave = tid >> 6, lane = tid & 63;
    int m0 = blockIdx.x * TM, n0 = blockIdx.y * TN;
    int srow = lane >> 2, schunk = lane & 3;
    const ushort* Ag = A + (size_t)(m0 + wave * (TM / 4) + srow) * K + schunk * 8;
    const ushort* Wg = W + (size_t)(n0 + wave * (TN / 4) + srow) * K + schunk * 8;
    ushort* Al = &As[(wave * (TM / 4)) * 32];
    ushort* Bl = &Bs[(wave * (TN / 4)) * 32];
    int lm = lane & 15, kq = lane >> 4;
    int wm = wave & 1, wn = wave >> 1;
    f32x4 acc[MI][NI];
#pragma unroll
    for (int i = 0; i < MI; ++i)
#pragma unroll
        for (int j = 0; j < NI; ++j) acc[i][j] = (f32x4)0.f;

    for (int k0 = 0; k0 < K; k0 += 32) {
#pragma unroll
        for (int i = 0; i < TM / 64; ++i)
            ASYNC_COPY16(Ag + k0 + (size_t)i * 16 * K, Al + i * 16 * 32);
#pragma unroll
        for (int i = 0; i < TN / 64; ++i)
            ASYNC_COPY16(Wg + k0 + (size_t)i * 16 * K, Bl + i * 16 * 32);
        __syncthreads();
        bf16x8 af[MI], bf[NI];
#pragma unroll
        for (int i = 0; i < MI; ++i)
            af[i] = *(const bf16x8*)&As[(wm * (TM / 2) + i * 16 + lm) * 32 + kq * 8];
#pragma unroll
        for (int j = 0; j < NI; ++j)
            bf[j] = *(const bf16x8*)&Bs[(wn * (TN / 2) + j * 16 + lm) * 32 + kq * 8];
#pragma unroll
        for (int i = 0; i < MI; ++i)
#pragma unroll
            for (int j = 0; j < NI; ++j)
                acc[i][j] = __builtin_amdgcn_mfma_f32_16x16x32_bf16(af[i], bf[j], acc[i][j], 0, 0, 0);
        __syncthreads();
    }
#pragma unroll
    for (int i = 0; i < MI; ++i)
#pragma unroll
        for (int j = 0; j < NI; ++j) {
            int col = n0 + wn * (TN / 2) + j * 16 + lm;
            float bv = bias[col];
#pragma unroll
            for (int r = 0; r < 4; ++r) {
                int row = m0 + wm * (TM / 2) + i * 16 + kq * 4 + r;
                float v = acc[i][j][r] + bv;
                if (MODE == 1) {
                    v = 0.5f * v * (1.f + erff(v * 0.70710678118654752f));
                    ((ushort*)outp)[(size_t)row * NC + col] = f2bf(v);
                } else {
                    v += res[(size_t)row * NC + col];
                    ((float*)outp)[(size_t)row * NC + col] = v;
                }
            }
        }
}

// ---------------- head: filt[m][n] = sum_{k,c} h[b, clamp(t+k-3)][c] * wk[k][n][c] + b_out[n]
// output written as bf16 (consumed by fir_mfma)
__global__ __launch_bounds__(256) void head_mfma(
    const ushort* __restrict__ H, const ushort* __restrict__ WK,
    const float* __restrict__ bias, ushort* __restrict__ out) {
    constexpr int TM = 128, TN = 128, MI = 4, NI = 4;
    __shared__ ushort As[TM * 32];
    __shared__ ushort Bs[TN * 32];
    int tid = threadIdx.x;
    int wave = tid >> 6, lane = tid & 63;
    int m0 = blockIdx.x * TM, n0 = blockIdx.y * TN;
    int b = m0 >> 9, tbase = m0 & (NT - 1);
    int srow = lane >> 2, schunk = lane & 3;
    ushort* Al = &As[(wave * 32) * 32];
    ushort* Bl = &Bs[(wave * 32) * 32];
    int lm = lane & 15, kq = lane >> 4;
    int wm = wave & 1, wn = wave >> 1;
    f32x4 acc[MI][NI];
#pragma unroll
    for (int i = 0; i < MI; ++i)
#pragma unroll
        for (int j = 0; j < NI; ++j) acc[i][j] = (f32x4)0.f;

    for (int k = 0; k < 7; ++k) {
        const ushort* ag[2];
#pragma unroll
        for (int i = 0; i < 2; ++i) {
            int t = tbase + wave * 32 + i * 16 + srow + k - 3;
            t = min(max(t, 0), NT - 1);
            ag[i] = H + ((size_t)(b << 9) + t) * CI + schunk * 8;
        }
        const ushort* wg = WK + ((size_t)k * NW + n0 + wave * 32 + srow) * CI + schunk * 8;
        for (int c0 = 0; c0 < CI; c0 += 32) {
#pragma unroll
            for (int i = 0; i < 2; ++i)
                ASYNC_COPY16(ag[i] + c0, Al + i * 16 * 32);
#pragma unroll
            for (int i = 0; i < 2; ++i)
                ASYNC_COPY16(wg + c0 + (size_t)i * 16 * CI, Bl + i * 16 * 32);
            __syncthreads();
            bf16x8 af[MI], bf[NI];
#pragma unroll
            for (int i = 0; i < MI; ++i)
                af[i] = *(const bf16x8*)&As[(wm * 64 + i * 16 + lm) * 32 + kq * 8];
#pragma unroll
            for (int j = 0; j < NI; ++j)
                bf[j] = *(const bf16x8*)&Bs[(wn * 64 + j * 16 + lm) * 32 + kq * 8];
#pragma unroll
            for (int i = 0; i < MI; ++i)
#pragma unroll
                for (int j = 0; j < NI; ++j)
                    acc[i][j] = __builtin_amdgcn_mfma_f32_16x16x32_bf16(af[i], bf[j], acc[i][j], 0, 0, 0);
            __syncthreads();
        }
    }
#pragma unroll
    for (int i = 0; i < MI; ++i)
#pragma unroll
        for (int j = 0; j < NI; ++j) {
            int col = n0 + wn * 64 + j * 16 + lm;
            float bv = bias[col];
#pragma unroll
            for (int r = 0; r < 4; ++r) {
                int row = m0 + wm * 64 + i * 16 + kq * 4 + r;
                out[(size_t)row * NW + col] = f2bf(acc[i][j][r] + bv);
            }
        }
}

// ---------------- dw conv + LN (wave-per-row, channels strided by 64)
template <bool DW>
__global__ __launch_bounds__(256) void dwln_kernel(const float* __restrict__ X, ushort* __restrict__ H,
                                                   const float* __restrict__ dw_w,
                                                   const float* __restrict__ dw_b,
                                                   const float* __restrict__ g,
                                                   const float* __restrict__ bb) {
    __shared__ float wt[7][512];
    int tid = threadIdx.x;
    if (DW) {
        for (int i = tid; i < 3584; i += 256) {
            int c = i / 7, k = i - c * 7;
            wt[k][c] = dw_w[i];
        }
        __syncthreads();
    }
    int wid = tid >> 6, lane = tid & 63;
    int n = blockIdx.x * 4 + wid;
    int b = n >> 9, t = n & (NT - 1);
    float v[8];
    if (DW) {
#pragma unroll
        for (int i = 0; i < 8; ++i) v[i] = dw_b[lane + 64 * i];
#pragma unroll
        for (int k = 0; k < 7; ++k) {
            int tt = t + k - 3;
            if (tt >= 0 && tt < NT) {
                const float* xr = X + ((size_t)(b << 9) + tt) * CI + lane;
#pragma unroll
                for (int i = 0; i < 8; ++i)
                    v[i] = fmaf(wt[k][lane + 64 * i], xr[64 * i], v[i]);
            }
        }
    } else {
        const float* xr = X + (size_t)n * CI + lane;
#pragma unroll
        for (int i = 0; i < 8; ++i) v[i] = xr[64 * i];
    }
    float s1 = 0.f, s2 = 0.f;
#pragma unroll
    for (int i = 0; i < 8; ++i) { s1 += v[i]; s2 = fmaf(v[i], v[i], s2); }
#pragma unroll
    for (int off = 1; off < 64; off <<= 1) {
        s1 += __shfl_xor(s1, off);
        s2 += __shfl_xor(s2, off);
    }
    float mean = s1 * (1.f / CI);
    float rs = rsqrtf(s2 * (1.f / CI) - mean * mean + 1e-6f);
    ushort* hr = H + (size_t)n * CI + lane;
#pragma unroll
    for (int i = 0; i < 8; ++i) {
        int c = lane + 64 * i;
        hr[64 * i] = f2bf((v[i] - mean) * rs * g[c] + bb[c]);
    }
}

// ---------------- FIR as Toeplitz MFMA GEMM (one block per frame)
// conv[16*ub + ul] = sum_k A[ub][k] * B[k][ul],
//   A[m][k] = s[16m + k - 1040]  (read directly from padded LDS, row stride 16)
//   B[k][ul] = f[k - ul - 16]    (16 shifted filter copies, built once per frame)
__global__ __launch_bounds__(256) void fir_mfma(const float* __restrict__ source,
                                                const ushort* __restrict__ filt,
                                                float* __restrict__ conv) {
    __shared__ ushort sp[3088];         // s at [1040, 2000), zeros elsewhere
    __shared__ ushort Bcm[16][1056];    // Bcm[ul][k]
    int tid = threadIdx.x;
    int bg = blockIdx.x;
    int b = bg >> 9, g = bg & (NT - 1);
    // zero the pad regions (disjoint from the source fill -> no barrier needed between)
    for (int i = tid; i < 520; i += 256) ((unsigned*)sp)[i] = 0;            // [0,1040)
    for (int i = tid; i < 544; i += 256) ((unsigned*)sp)[1000 + i] = 0;     // [2000,3088)
    if (tid < 240) {
        float4 sv = ((const float4*)(source + (size_t)b * LTOT + g * FS))[tid];
        ushort4 o; o.x = f2bf(sv.x); o.y = f2bf(sv.y); o.z = f2bf(sv.z); o.w = f2bf(sv.w);
        *(ushort4*)&sp[1040 + tid * 4] = o;
    }
    // build 16 shifted filter copies (bf16 passthrough from global)
    const ushort* fr = filt + (size_t)bg * NW;
#pragma unroll
    for (int ul = 0; ul < 16; ++ul)
        for (int k = tid; k < 1056; k += 256) {
            int fi = k - ul - 16;
            Bcm[ul][k] = (fi >= 0 && fi < 1024) ? fr[fi] : (ushort)0;
        }
    __syncthreads();

    int wave = tid >> 6, lane = tid & 63;
    int ln = lane & 15, kq = lane >> 4;
    const ushort* Abase = &sp[16 * ln + 8 * kq];
    const ushort* Bbase = &Bcm[ln][8 * kq];
    int mt0 = wave * 2;
    f32x4 acc0 = (f32x4)0.f, acc1 = (f32x4)0.f;
#pragma unroll 3
    for (int kt = 0; kt < 33; ++kt) {
        bf16x8 bfrag = *(const bf16x8*)(Bbase + 32 * kt);
        bf16x8 a0 = *(const bf16x8*)(Abase + 256 * mt0 + 32 * kt);
        bf16x8 a1 = *(const bf16x8*)(Abase + 256 * (mt0 + 1) + 32 * kt);
        acc0 = __builtin_amdgcn_mfma_f32_16x16x32_bf16(a0, bfrag, acc0, 0, 0, 0);
        acc1 = __builtin_amdgcn_mfma_f32_16x16x32_bf16(a1, bfrag, acc1, 0, 0, 0);
    }
    float* cv = conv + (size_t)bg * CONVW;
#pragma unroll
    for (int r = 0; r < 4; ++r) {
        int m0 = mt0 * 16 + kq * 4 + r;
        cv[16 * m0 + ln] = acc0[r];                  // m0 <= 111 always valid
        int m1 = m0 + 16;
        if (m1 < 124) cv[16 * m1 + ln] = acc1[r];
    }
}

// ---------------- overlap-add fold
__global__ void fold_kernel(const float* __restrict__ conv, float* __restrict__ out) {
    int b = blockIdx.y;
    int t = blockIdx.x * blockDim.x + threadIdx.x;
    float sum = 0.f;
    int G = (t - 1) / 960;
#pragma unroll
    for (int r = 0; r < 3; ++r) {
        int g = G - r;
        if (g >= 0) {
            int u = t - 960 * g;
            if (u < CONVW) sum += conv[((size_t)(b * NT + g)) * CONVW + u];
        }
    }
    out[(size_t)b * LTOT + t] = sum;
}

extern "C" void kernel_launch(void* const* d_in, const int* in_sizes, int n_in,
                              void* d_out, int out_size, void* d_ws, size_t ws_size,
                              hipStream_t stream) {
    const float* content  = (const float*)d_in[0];
    const float* f0       = (const float*)d_in[1];
    const float* energy   = (const float*)d_in[2];
    const float* spk      = (const float*)d_in[3];
    const float* source   = (const float*)d_in[4];
    const float* w_content= (const float*)d_in[5];
    const float* b_content= (const float*)d_in[6];
    const float* w_spk    = (const float*)d_in[7];
    const float* b_spk    = (const float*)d_in[8];
    const float* w_f0     = (const float*)d_in[9];
    const float* b_f0     = (const float*)d_in[10];
    const float* w_energy = (const float*)d_in[11];
    const float* b_energy = (const float*)d_in[12];
    const float* dw_w     = (const float*)d_in[13];
    const float* dw_b     = (const float*)d_in[14];
    const float* ln_g     = (const float*)d_in[15];
    const float* ln_b     = (const float*)d_in[16];
    const float* pw1_w    = (const float*)d_in[17];
    const float* pw1_b    = (const float*)d_in[18];
    const float* pw2_w    = (const float*)d_in[19];
    const float* pw2_b    = (const float*)d_in[20];
    const float* out_ln_g = (const float*)d_in[21];
    const float* out_ln_b = (const float*)d_in[22];
    const float* w_out    = (const float*)d_in[23];
    const float* b_out    = (const float*)d_in[24];
    float* out = (float*)d_out;

    float* ws = (float*)d_ws;
    float*  x     = ws;                              // 2,097,152 f
    float*  base  = ws + 2097152;                    // 4,096 f
    float*  ct    = ws + 2101248;                    // 786,432 f
    ushort* filtb = (ushort*)(ws + 2887680);         // 4,194,304 bf16 (uses half the old region)
    ushort* h     = (ushort*)(ws + 7081984);         // 2,097,152 bf16
    ushort* pw1w  = (ushort*)(ws + 8130560);         // 2,359,296 f worth
    ushort* pw2w  = (ushort*)(ws + 10489856);
    ushort* wk    = (ushort*)(ws + 12849152);
    ushort* hmid  = (ushort*)(ws + 14684160);
    float*  conv  = ws + 8130560;                    // 8,126,464 f (overlays weights, dead by then)

    cvt_bf16<<<4608, 256, 0, stream>>>(pw1_w, pw1w, 1179648);
    cvt_bf16<<<4608, 256, 0, stream>>>(pw2_w, pw2w, 1179648);
    cvt_wout<<<NW, 256, 0, stream>>>(w_out, wk);
    spkbase_kernel<<<NB, 256, 0, stream>>>(spk, w_spk, b_spk, b_content, b_f0, b_energy, base);
    transpose_content<<<dim3(16, 6, NB), dim3(32, 8), 0, stream>>>(content, ct);

    gemm_trunk<<<dim3(NROWS / TILE, CI / TILE), 256, 0, stream>>>(
        ct, w_content, x, base, f0, energy, w_f0, w_energy);

    for (int i = 0; i < 6; ++i) {
        dwln_kernel<true><<<NROWS / 4, 256, 0, stream>>>(x, h, dw_w + i * CI * 7, dw_b + i * CI,
                                                         ln_g + i * CI, ln_b + i * CI);
        gemm_mfma<1, 128, 128><<<dim3(NROWS / 128, DM / 128), 256, 0, stream>>>(
            h, pw1w + (size_t)i * DM * CI, pw1_b + i * DM, hmid, nullptr, CI, DM);
        gemm_mfma<2, 128, 64><<<dim3(NROWS / 128, CI / 64), 256, 0, stream>>>(
            hmid, pw2w + (size_t)i * CI * DM, pw2_b + i * CI, x, x, DM, CI);
    }

    dwln_kernel<false><<<NROWS / 4, 256, 0, stream>>>(x, h, nullptr, nullptr, out_ln_g, out_ln_b);
    head_mfma<<<dim3(NROWS / 128, NW / 128), 256, 0, stream>>>(h, wk, b_out, filtb);
    fir_mfma<<<NROWS, 256, 0, stream>>>(source, filtb, conv);
    fold_kernel<<<dim3(LTOT / 256, NB), 256, 0, stream>>>(conv, out);
}

// Round 5
// 681.588 us; speedup vs baseline: 1.5588x; 1.0081x over previous
//
#include <hip/hip_runtime.h>
#include <math.h>

// Problem constants
#define NB 8
#define NT 512           // N_FRAMES
#define NROWS 4096       // NB*NT
#define CI 512           // C_INT
#define DM 1536          // D_MLP
#define CCON 192
#define CSPK 256
#define NW 1024          // N_WINDOW
#define FS 960           // FRAME_SIZE
#define LTOT 491520      // NT*FS
#define CONVW 1984       // FS+NW

typedef __bf16 bf16x8 __attribute__((ext_vector_type(8)));
typedef float f32x4 __attribute__((ext_vector_type(4)));
typedef unsigned short ushort;

__device__ __forceinline__ ushort f2bf(float x) {
    union { float f; unsigned u; } v; v.f = x;
    unsigned r = v.u + 0x7fff + ((v.u >> 16) & 1);
    return (ushort)(r >> 16);
}

#define ASYNC_COPY16(g, l) __builtin_amdgcn_global_load_lds( \
    (const __attribute__((address_space(1))) void*)(g), \
    (__attribute__((address_space(3))) void*)(l), 16, 0, 0)

// ---------------- weight fp32 -> bf16 (elementwise, 4/thread)
__global__ void cvt_bf16(const float* __restrict__ in, ushort* __restrict__ out, int n4) {
    int i = blockIdx.x * 256 + threadIdx.x;
    if (i < n4) {
        float4 v = ((const float4*)in)[i];
        ushort4 o; o.x = f2bf(v.x); o.y = f2bf(v.y); o.z = f2bf(v.z); o.w = f2bf(v.w);
        ((ushort4*)out)[i] = o;
    }
}

// ---------------- w_out (NW, CI, 7) -> wk[k][n][c] bf16
__global__ void cvt_wout(const float* __restrict__ w, ushort* __restrict__ wk) {
    int n = blockIdx.x, tid = threadIdx.x;
    __shared__ ushort s[7][512];
#pragma unroll
    for (int h = 0; h < 2; ++h) {
        int c = tid + h * 256;
        const float* p = w + ((size_t)n * 512 + c) * 7;
#pragma unroll
        for (int k = 0; k < 7; ++k) s[k][c] = f2bf(p[k]);
    }
    __syncthreads();
#pragma unroll
    for (int k = 0; k < 7; ++k)
#pragma unroll
        for (int h = 0; h < 2; ++h) {
            int c = tid + h * 256;
            wk[((size_t)k * NW + n) * CI + c] = s[k][c];
        }
}

// ---------------- spk base
__global__ void spkbase_kernel(const float* __restrict__ spk, const float* __restrict__ w_spk,
                               const float* __restrict__ b_spk, const float* __restrict__ b_content,
                               const float* __restrict__ b_f0, const float* __restrict__ b_energy,
                               float* __restrict__ base) {
    int b = blockIdx.x, tid = threadIdx.x;
    __shared__ float s[CSPK];
    if (tid < CSPK) s[tid] = spk[b * CSPK + tid];
    __syncthreads();
    for (int o = tid; o < CI; o += 256) {
        float acc = 0.f;
        for (int c = 0; c < CSPK; ++c) acc = fmaf(w_spk[o * CSPK + c], s[c], acc);
        base[b * CI + o] = acc + b_spk[o] + b_content[o] + b_f0[o] + b_energy[o];
    }
}

// ---------------- content transpose: (B, 192, T) -> ct[(b*T+t)][c] (bf16)
__global__ void transpose_content(const float* __restrict__ content, ushort* __restrict__ ct) {
    __shared__ float tile[32][33];
    int b = blockIdx.z, c0 = blockIdx.y * 32, t0 = blockIdx.x * 32;
    int x = threadIdx.x, y = threadIdx.y;
#pragma unroll
    for (int i = 0; i < 32; i += 8)
        tile[y + i][x] = content[((size_t)b * CCON + c0 + y + i) * NT + t0 + x];
    __syncthreads();
#pragma unroll
    for (int i = 0; i < 32; i += 8)
        ct[((size_t)b * NT + t0 + y + i) * CCON + c0 + x] = f2bf(tile[x][y + i]);
}

// ---------------- unified bf16 MFMA GEMM, double-buffered single-barrier K-loop
// out[m][n] = epi( sum_k A[m][k] * W[n][k] )
// MODE 0: trunk epilogue (+base +w_f0*logf0 +w_energy*energy), fp32 out
// MODE 1: +bias, gelu, bf16 out
// MODE 2: +bias +residual(fp32), fp32 out
template <int MODE, int TM, int TN>
__global__ __launch_bounds__(256) void gemm_mfma(
    const ushort* __restrict__ A, const ushort* __restrict__ W,
    const float* __restrict__ bias, void* __restrict__ outp,
    const float* __restrict__ res, int K, int NC,
    const float* __restrict__ f0, const float* __restrict__ energy,
    const float* __restrict__ w_f0, const float* __restrict__ w_energy,
    const float* __restrict__ base) {
    constexpr int MI = TM / 32, NI = TN / 32;
    __shared__ ushort As[2][TM * 32];
    __shared__ ushort Bs[2][TN * 32];
    int tid = threadIdx.x;
    int wave = tid >> 6, lane = tid & 63;
    int m0 = blockIdx.x * TM, n0 = blockIdx.y * TN;
    int srow = lane >> 2, schunk = lane & 3;
    const ushort* Ag = A + (size_t)(m0 + wave * (TM / 4) + srow) * K + schunk * 8;
    const ushort* Wg = W + (size_t)(n0 + wave * (TN / 4) + srow) * K + schunk * 8;
    const int aoff = wave * (TM / 4) * 32;
    const int boff = wave * (TN / 4) * 32;
    int lm = lane & 15, kq = lane >> 4;
    int wm = wave & 1, wn = wave >> 1;
    f32x4 acc[MI][NI];
#pragma unroll
    for (int i = 0; i < MI; ++i)
#pragma unroll
        for (int j = 0; j < NI; ++j) acc[i][j] = (f32x4)0.f;

    auto stage = [&](int buf, int k0) {
#pragma unroll
        for (int i = 0; i < TM / 64; ++i)
            ASYNC_COPY16(Ag + k0 + (size_t)i * 16 * K, &As[buf][aoff + i * 16 * 32]);
#pragma unroll
        for (int i = 0; i < TN / 64; ++i)
            ASYNC_COPY16(Wg + k0 + (size_t)i * 16 * K, &Bs[buf][boff + i * 16 * 32]);
    };

    const int nk = K >> 5;
    stage(0, 0);
    for (int it = 0; it < nk; ++it) {
        __syncthreads();
        if (it + 1 < nk) stage((it + 1) & 1, (it + 1) << 5);
        int cur = it & 1;
        bf16x8 af[MI], bf[NI];
#pragma unroll
        for (int i = 0; i < MI; ++i)
            af[i] = *(const bf16x8*)&As[cur][(wm * (TM / 2) + i * 16 + lm) * 32 + kq * 8];
#pragma unroll
        for (int j = 0; j < NI; ++j)
            bf[j] = *(const bf16x8*)&Bs[cur][(wn * (TN / 2) + j * 16 + lm) * 32 + kq * 8];
#pragma unroll
        for (int i = 0; i < MI; ++i)
#pragma unroll
            for (int j = 0; j < NI; ++j)
                acc[i][j] = __builtin_amdgcn_mfma_f32_16x16x32_bf16(af[i], bf[j], acc[i][j], 0, 0, 0);
    }

    int colv[NI];
#pragma unroll
    for (int j = 0; j < NI; ++j) colv[j] = n0 + wn * (TN / 2) + j * 16 + lm;
    float p0[NI], p1[NI], p2[NI];
#pragma unroll
    for (int j = 0; j < NI; ++j) {
        if (MODE == 0) {
            int bb = m0 >> 9;   // 128-row tiles never straddle a batch
            p0[j] = base[(bb << 9) + colv[j]];
            p1[j] = w_f0[colv[j]];
            p2[j] = w_energy[colv[j]];
        } else {
            p0[j] = bias[colv[j]];
        }
    }
#pragma unroll
    for (int i = 0; i < MI; ++i)
#pragma unroll
        for (int r = 0; r < 4; ++r) {
            int row = m0 + wm * (TM / 2) + i * 16 + kq * 4 + r;
            float fv = 0.f, ev = 0.f;
            if (MODE == 0) {
                fv = logf(fmaxf(f0[row], 0.f) + 1e-6f);
                ev = energy[row];
            }
#pragma unroll
            for (int j = 0; j < NI; ++j) {
                float v = acc[i][j][r];
                if (MODE == 0) {
                    v += p0[j] + p1[j] * fv + p2[j] * ev;
                    ((float*)outp)[(size_t)row * NC + colv[j]] = v;
                } else if (MODE == 1) {
                    v += p0[j];
                    v = 0.5f * v * (1.f + erff(v * 0.70710678118654752f));
                    ((ushort*)outp)[(size_t)row * NC + colv[j]] = f2bf(v);
                } else {
                    v += p0[j] + res[(size_t)row * NC + colv[j]];
                    ((float*)outp)[(size_t)row * NC + colv[j]] = v;
                }
            }
        }
}

// ---------------- head: filt[m][n] = sum_{k,c} h[b, clamp(t+k-3)][c] * wk[k][n][c] + b_out[n]
// double-buffered flattened (k,c0) loop; bf16 out (consumed by fir_mfma)
__global__ __launch_bounds__(256) void head_mfma(
    const ushort* __restrict__ H, const ushort* __restrict__ WK,
    const float* __restrict__ bias, ushort* __restrict__ out) {
    constexpr int MI = 4, NI = 4;
    __shared__ ushort As[2][128 * 32];
    __shared__ ushort Bs[2][128 * 32];
    int tid = threadIdx.x;
    int wave = tid >> 6, lane = tid & 63;
    int m0 = blockIdx.x * 128, n0 = blockIdx.y * 128;
    int b = m0 >> 9, tbase = m0 & (NT - 1);
    int srow = lane >> 2, schunk = lane & 3;
    const int aoff = wave * 32 * 32;
    int lm = lane & 15, kq = lane >> 4;
    int wm = wave & 1, wn = wave >> 1;
    f32x4 acc[MI][NI];
#pragma unroll
    for (int i = 0; i < MI; ++i)
#pragma unroll
        for (int j = 0; j < NI; ++j) acc[i][j] = (f32x4)0.f;

    auto stage = [&](int buf, int it) {
        int k = it >> 4, c0 = (it & 15) << 5;
#pragma unroll
        for (int i = 0; i < 2; ++i) {
            int t = tbase + wave * 32 + i * 16 + srow + k - 3;
            t = min(max(t, 0), NT - 1);
            ASYNC_COPY16(H + ((size_t)(b << 9) + t) * CI + c0 + schunk * 8,
                         &As[buf][aoff + i * 16 * 32]);
        }
        const ushort* wg = WK + ((size_t)k * NW + n0 + wave * 32 + srow) * CI + c0 + schunk * 8;
#pragma unroll
        for (int i = 0; i < 2; ++i)
            ASYNC_COPY16(wg + (size_t)i * 16 * CI, &Bs[buf][aoff + i * 16 * 32]);
    };

    stage(0, 0);
    for (int it = 0; it < 112; ++it) {
        __syncthreads();
        if (it + 1 < 112) stage((it + 1) & 1, it + 1);
        int cur = it & 1;
        bf16x8 af[MI], bf[NI];
#pragma unroll
        for (int i = 0; i < MI; ++i)
            af[i] = *(const bf16x8*)&As[cur][(wm * 64 + i * 16 + lm) * 32 + kq * 8];
#pragma unroll
        for (int j = 0; j < NI; ++j)
            bf[j] = *(const bf16x8*)&Bs[cur][(wn * 64 + j * 16 + lm) * 32 + kq * 8];
#pragma unroll
        for (int i = 0; i < MI; ++i)
#pragma unroll
            for (int j = 0; j < NI; ++j)
                acc[i][j] = __builtin_amdgcn_mfma_f32_16x16x32_bf16(af[i], bf[j], acc[i][j], 0, 0, 0);
    }
#pragma unroll
    for (int i = 0; i < MI; ++i)
#pragma unroll
        for (int j = 0; j < NI; ++j) {
            int col = n0 + wn * 64 + j * 16 + lm;
            float bv = bias[col];
#pragma unroll
            for (int r = 0; r < 4; ++r) {
                int row = m0 + wm * 64 + i * 16 + kq * 4 + r;
                out[(size_t)row * NW + col] = f2bf(acc[i][j][r] + bv);
            }
        }
}

// ---------------- dw conv + LN (wave-per-row, channels strided by 64)
template <bool DW>
__global__ __launch_bounds__(256) void dwln_kernel(const float* __restrict__ X, ushort* __restrict__ H,
                                                   const float* __restrict__ dw_w,
                                                   const float* __restrict__ dw_b,
                                                   const float* __restrict__ g,
                                                   const float* __restrict__ bb) {
    __shared__ float wt[7][512];
    int tid = threadIdx.x;
    if (DW) {
        for (int i = tid; i < 3584; i += 256) {
            int c = i / 7, k = i - c * 7;
            wt[k][c] = dw_w[i];
        }
        __syncthreads();
    }
    int wid = tid >> 6, lane = tid & 63;
    int n = blockIdx.x * 4 + wid;
    int b = n >> 9, t = n & (NT - 1);
    float v[8];
    if (DW) {
#pragma unroll
        for (int i = 0; i < 8; ++i) v[i] = dw_b[lane + 64 * i];
#pragma unroll
        for (int k = 0; k < 7; ++k) {
            int tt = t + k - 3;
            if (tt >= 0 && tt < NT) {
                const float* xr = X + ((size_t)(b << 9) + tt) * CI + lane;
#pragma unroll
                for (int i = 0; i < 8; ++i)
                    v[i] = fmaf(wt[k][lane + 64 * i], xr[64 * i], v[i]);
            }
        }
    } else {
        const float* xr = X + (size_t)n * CI + lane;
#pragma unroll
        for (int i = 0; i < 8; ++i) v[i] = xr[64 * i];
    }
    float s1 = 0.f, s2 = 0.f;
#pragma unroll
    for (int i = 0; i < 8; ++i) { s1 += v[i]; s2 = fmaf(v[i], v[i], s2); }
#pragma unroll
    for (int off = 1; off < 64; off <<= 1) {
        s1 += __shfl_xor(s1, off);
        s2 += __shfl_xor(s2, off);
    }
    float mean = s1 * (1.f / CI);
    float rs = rsqrtf(s2 * (1.f / CI) - mean * mean + 1e-6f);
    ushort* hr = H + (size_t)n * CI + lane;
#pragma unroll
    for (int i = 0; i < 8; ++i) {
        int c = lane + 64 * i;
        hr[64 * i] = f2bf((v[i] - mean) * rs * g[c] + bb[c]);
    }
}

// ---------------- FIR as Toeplitz MFMA GEMM (one block per frame)
__global__ __launch_bounds__(256) void fir_mfma(const float* __restrict__ source,
                                                const ushort* __restrict__ filt,
                                                float* __restrict__ conv) {
    __shared__ ushort sp[3088];         // s at [1040, 2000), zeros elsewhere
    __shared__ ushort Bcm[16][1056];    // Bcm[ul][k]
    int tid = threadIdx.x;
    int bg = blockIdx.x;
    int b = bg >> 9, g = bg & (NT - 1);
    for (int i = tid; i < 520; i += 256) ((unsigned*)sp)[i] = 0;            // [0,1040)
    for (int i = tid; i < 544; i += 256) ((unsigned*)sp)[1000 + i] = 0;     // [2000,3088)
    if (tid < 240) {
        float4 sv = ((const float4*)(source + (size_t)b * LTOT + g * FS))[tid];
        ushort4 o; o.x = f2bf(sv.x); o.y = f2bf(sv.y); o.z = f2bf(sv.z); o.w = f2bf(sv.w);
        *(ushort4*)&sp[1040 + tid * 4] = o;
    }
    const ushort* fr = filt + (size_t)bg * NW;
#pragma unroll
    for (int ul = 0; ul < 16; ++ul)
        for (int k = tid; k < 1056; k += 256) {
            int fi = k - ul - 16;
            Bcm[ul][k] = (fi >= 0 && fi < 1024) ? fr[fi] : (ushort)0;
        }
    __syncthreads();

    int wave = tid >> 6, lane = tid & 63;
    int ln = lane & 15, kq = lane >> 4;
    const ushort* Abase = &sp[16 * ln + 8 * kq];
    const ushort* Bbase = &Bcm[ln][8 * kq];
    int mt0 = wave * 2;
    f32x4 acc0 = (f32x4)0.f, acc1 = (f32x4)0.f;
#pragma unroll 3
    for (int kt = 0; kt < 33; ++kt) {
        bf16x8 bfrag = *(const bf16x8*)(Bbase + 32 * kt);
        bf16x8 a0 = *(const bf16x8*)(Abase + 256 * mt0 + 32 * kt);
        bf16x8 a1 = *(const bf16x8*)(Abase + 256 * (mt0 + 1) + 32 * kt);
        acc0 = __builtin_amdgcn_mfma_f32_16x16x32_bf16(a0, bfrag, acc0, 0, 0, 0);
        acc1 = __builtin_amdgcn_mfma_f32_16x16x32_bf16(a1, bfrag, acc1, 0, 0, 0);
    }
    float* cv = conv + (size_t)bg * CONVW;
#pragma unroll
    for (int r = 0; r < 4; ++r) {
        int m0 = mt0 * 16 + kq * 4 + r;
        cv[16 * m0 + ln] = acc0[r];
        int m1 = m0 + 16;
        if (m1 < 124) cv[16 * m1 + ln] = acc1[r];
    }
}

// ---------------- overlap-add fold
__global__ void fold_kernel(const float* __restrict__ conv, float* __restrict__ out) {
    int b = blockIdx.y;
    int t = blockIdx.x * blockDim.x + threadIdx.x;
    float sum = 0.f;
    int G = (t - 1) / 960;
#pragma unroll
    for (int r = 0; r < 3; ++r) {
        int g = G - r;
        if (g >= 0) {
            int u = t - 960 * g;
            if (u < CONVW) sum += conv[((size_t)(b * NT + g)) * CONVW + u];
        }
    }
    out[(size_t)b * LTOT + t] = sum;
}

extern "C" void kernel_launch(void* const* d_in, const int* in_sizes, int n_in,
                              void* d_out, int out_size, void* d_ws, size_t ws_size,
                              hipStream_t stream) {
    const float* content  = (const float*)d_in[0];
    const float* f0       = (const float*)d_in[1];
    const float* energy   = (const float*)d_in[2];
    const float* spk      = (const float*)d_in[3];
    const float* source   = (const float*)d_in[4];
    const float* w_content= (const float*)d_in[5];
    const float* b_content= (const float*)d_in[6];
    const float* w_spk    = (const float*)d_in[7];
    const float* b_spk    = (const float*)d_in[8];
    const float* w_f0     = (const float*)d_in[9];
    const float* b_f0     = (const float*)d_in[10];
    const float* w_energy = (const float*)d_in[11];
    const float* b_energy = (const float*)d_in[12];
    const float* dw_w     = (const float*)d_in[13];
    const float* dw_b     = (const float*)d_in[14];
    const float* ln_g     = (const float*)d_in[15];
    const float* ln_b     = (const float*)d_in[16];
    const float* pw1_w    = (const float*)d_in[17];
    const float* pw1_b    = (const float*)d_in[18];
    const float* pw2_w    = (const float*)d_in[19];
    const float* pw2_b    = (const float*)d_in[20];
    const float* out_ln_g = (const float*)d_in[21];
    const float* out_ln_b = (const float*)d_in[22];
    const float* w_out    = (const float*)d_in[23];
    const float* b_out    = (const float*)d_in[24];
    float* out = (float*)d_out;

    float* ws = (float*)d_ws;
    // layout (float offsets)
    float*  x     = ws;                              // 2,097,152 f
    float*  base  = ws + 2097152;                    // 4,096 f
    ushort* ctb   = (ushort*)(ws + 2101248);         // 786,432 bf16 (393,216 f)
    ushort* wcb   = (ushort*)(ws + 2494464);         // 98,304 bf16 (49,152 f)
    ushort* filtb = (ushort*)(ws + 2543616);         // 4,194,304 bf16 (2,097,152 f)
    ushort* h     = (ushort*)(ws + 4640768);         // 2,097,152 bf16 (1,048,576 f)
    ushort* pw1w  = (ushort*)(ws + 5689344);         // 4,718,592 bf16 (2,359,296 f)
    ushort* pw2w  = (ushort*)(ws + 8048640);         // 4,718,592 bf16 (2,359,296 f)
    ushort* wk    = (ushort*)(ws + 10407936);        // 3,670,016 bf16 (1,835,008 f)
    ushort* hmid  = (ushort*)(ws + 12242944);        // 6,291,456 bf16 (3,145,728 f)
    float*  conv  = ws + 5689344;                    // 8,126,464 f — overlays pw/wk/hmid (dead by fir)
    // total 15,388,672 f = 61.6 MB

    cvt_bf16<<<4608, 256, 0, stream>>>(pw1_w, pw1w, 1179648);
    cvt_bf16<<<4608, 256, 0, stream>>>(pw2_w, pw2w, 1179648);
    cvt_bf16<<<96, 256, 0, stream>>>(w_content, wcb, 24576);
    cvt_wout<<<NW, 256, 0, stream>>>(w_out, wk);
    spkbase_kernel<<<NB, 256, 0, stream>>>(spk, w_spk, b_spk, b_content, b_f0, b_energy, base);
    transpose_content<<<dim3(16, 6, NB), dim3(32, 8), 0, stream>>>(content, ctb);

    // trunk (bf16 MFMA, MODE 0): x = ctb @ wcb^T + base + w_f0*logf0 + w_energy*energy
    gemm_mfma<0, 128, 64><<<dim3(NROWS / 128, CI / 64), 256, 0, stream>>>(
        ctb, wcb, nullptr, x, nullptr, CCON, CI, f0, energy, w_f0, w_energy, base);

    for (int i = 0; i < 6; ++i) {
        dwln_kernel<true><<<NROWS / 4, 256, 0, stream>>>(x, h, dw_w + i * CI * 7, dw_b + i * CI,
                                                         ln_g + i * CI, ln_b + i * CI);
        gemm_mfma<1, 128, 128><<<dim3(NROWS / 128, DM / 128), 256, 0, stream>>>(
            h, pw1w + (size_t)i * DM * CI, pw1_b + i * DM, hmid, nullptr, CI, DM,
            nullptr, nullptr, nullptr, nullptr, nullptr);
        gemm_mfma<2, 128, 64><<<dim3(NROWS / 128, CI / 64), 256, 0, stream>>>(
            hmid, pw2w + (size_t)i * CI * DM, pw2_b + i * CI, x, x, DM, CI,
            nullptr, nullptr, nullptr, nullptr, nullptr);
    }

    dwln_kernel<false><<<NROWS / 4, 256, 0, stream>>>(x, h, nullptr, nullptr, out_ln_g, out_ln_b);
    head_mfma<<<dim3(NROWS / 128, NW / 128), 256, 0, stream>>>(h, wk, b_out, filtb);
    fir_mfma<<<NROWS, 256, 0, stream>>>(source, filtb, conv);
    fold_kernel<<<dim3(LTOT / 256, NB), 256, 0, stream>>>(conv, out);
}

// Round 6
// 595.263 us; speedup vs baseline: 1.7849x; 1.1450x over previous
//
#include <hip/hip_runtime.h>
#include <math.h>

// Problem constants
#define NB 8
#define NT 512           // N_FRAMES
#define NROWS 4096       // NB*NT
#define CI 512           // C_INT
#define DM 1536          // D_MLP
#define CCON 192
#define CSPK 256
#define NW 1024          // N_WINDOW
#define FS 960           // FRAME_SIZE
#define LTOT 491520      // NT*FS
#define CONVW 1984       // FS+NW

typedef __bf16 bf16x8 __attribute__((ext_vector_type(8)));
typedef float f32x4 __attribute__((ext_vector_type(4)));
typedef unsigned short ushort;

__device__ __forceinline__ ushort f2bf(float x) {
    union { float f; unsigned u; } v; v.f = x;
    unsigned r = v.u + 0x7fff + ((v.u >> 16) & 1);
    return (ushort)(r >> 16);
}

#define ASYNC_COPY16(g, l) __builtin_amdgcn_global_load_lds( \
    (const __attribute__((address_space(1))) void*)(g), \
    (__attribute__((address_space(3))) void*)(l), 16, 0, 0)

// ---------------- weight fp32 -> bf16 (elementwise, 4/thread)
__global__ void cvt_bf16(const float* __restrict__ in, ushort* __restrict__ out, int n4) {
    int i = blockIdx.x * 256 + threadIdx.x;
    if (i < n4) {
        float4 v = ((const float4*)in)[i];
        ushort4 o; o.x = f2bf(v.x); o.y = f2bf(v.y); o.z = f2bf(v.z); o.w = f2bf(v.w);
        ((ushort4*)out)[i] = o;
    }
}

// ---------------- w_out (NW, CI, 7) -> wk[k][n][c] bf16
__global__ void cvt_wout(const float* __restrict__ w, ushort* __restrict__ wk) {
    int n = blockIdx.x, tid = threadIdx.x;
    __shared__ ushort s[7][512];
#pragma unroll
    for (int h = 0; h < 2; ++h) {
        int c = tid + h * 256;
        const float* p = w + ((size_t)n * 512 + c) * 7;
#pragma unroll
        for (int k = 0; k < 7; ++k) s[k][c] = f2bf(p[k]);
    }
    __syncthreads();
#pragma unroll
    for (int k = 0; k < 7; ++k)
#pragma unroll
        for (int h = 0; h < 2; ++h) {
            int c = tid + h * 256;
            wk[((size_t)k * NW + n) * CI + c] = s[k][c];
        }
}

// ---------------- spk base
__global__ void spkbase_kernel(const float* __restrict__ spk, const float* __restrict__ w_spk,
                               const float* __restrict__ b_spk, const float* __restrict__ b_content,
                               const float* __restrict__ b_f0, const float* __restrict__ b_energy,
                               float* __restrict__ base) {
    int b = blockIdx.x, tid = threadIdx.x;
    __shared__ float s[CSPK];
    if (tid < CSPK) s[tid] = spk[b * CSPK + tid];
    __syncthreads();
    for (int o = tid; o < CI; o += 256) {
        float acc = 0.f;
        for (int c = 0; c < CSPK; ++c) acc = fmaf(w_spk[o * CSPK + c], s[c], acc);
        base[b * CI + o] = acc + b_spk[o] + b_content[o] + b_f0[o] + b_energy[o];
    }
}

// ---------------- content transpose: (B, 192, T) -> ct[(b*T+t)][c] (bf16)
__global__ void transpose_content(const float* __restrict__ content, ushort* __restrict__ ct) {
    __shared__ float tile[32][33];
    int b = blockIdx.z, c0 = blockIdx.y * 32, t0 = blockIdx.x * 32;
    int x = threadIdx.x, y = threadIdx.y;
#pragma unroll
    for (int i = 0; i < 32; i += 8)
        tile[y + i][x] = content[((size_t)b * CCON + c0 + y + i) * NT + t0 + x];
    __syncthreads();
#pragma unroll
    for (int i = 0; i < 32; i += 8)
        ct[((size_t)b * NT + t0 + y + i) * CCON + c0 + x] = f2bf(tile[x][y + i]);
}

// ---------------- 64x64 bf16 MFMA GEMM, single-buffered 2-barrier K-loop
// out[m][n] = epi( sum_k A[m][k] * W[n][k] )
// MODE 0: trunk epilogue (+base +w_f0*logf0 +w_energy*energy), fp32 out
// MODE 1: +bias, gelu, bf16 out
// MODE 2: +bias +residual(fp32), fp32 out
// 4 waves in 2x2; wave computes 32x32 (2x2 16x16x32 frags). 1 async issue /
// thread / operand / iter; LDS dest = wave*1024B + lane*16B (wave-uniform+lane rule).
template <int MODE>
__global__ __launch_bounds__(256) void gemm_mfma64(
    const ushort* __restrict__ A, const ushort* __restrict__ W,
    const float* __restrict__ bias, void* __restrict__ outp,
    const float* __restrict__ res, int K, int NC,
    const float* __restrict__ f0, const float* __restrict__ energy,
    const float* __restrict__ w_f0, const float* __restrict__ w_energy,
    const float* __restrict__ base) {
    __shared__ ushort As[64 * 32];
    __shared__ ushort Bs[64 * 32];
    int tid = threadIdx.x;
    int wave = tid >> 6, lane = tid & 63;
    int m0 = blockIdx.x * 64, n0 = blockIdx.y * 64;
    int srow = tid >> 2, schunk = tid & 3;
    const ushort* Ag = A + (size_t)(m0 + srow) * K + schunk * 8;
    const ushort* Wg = W + (size_t)(n0 + srow) * K + schunk * 8;
    const int ldst = srow * 32 + schunk * 8;
    int lm = lane & 15, kq = lane >> 4;
    int wm = wave & 1, wn = wave >> 1;
    f32x4 acc[2][2];
#pragma unroll
    for (int i = 0; i < 2; ++i)
#pragma unroll
        for (int j = 0; j < 2; ++j) acc[i][j] = (f32x4)0.f;

    for (int k0 = 0; k0 < K; k0 += 32) {
        ASYNC_COPY16(Ag + k0, &As[ldst]);
        ASYNC_COPY16(Wg + k0, &Bs[ldst]);
        __syncthreads();
        bf16x8 af[2], bf[2];
#pragma unroll
        for (int i = 0; i < 2; ++i)
            af[i] = *(const bf16x8*)&As[(wm * 32 + i * 16 + lm) * 32 + kq * 8];
#pragma unroll
        for (int j = 0; j < 2; ++j)
            bf[j] = *(const bf16x8*)&Bs[(wn * 32 + j * 16 + lm) * 32 + kq * 8];
#pragma unroll
        for (int i = 0; i < 2; ++i)
#pragma unroll
            for (int j = 0; j < 2; ++j)
                acc[i][j] = __builtin_amdgcn_mfma_f32_16x16x32_bf16(af[i], bf[j], acc[i][j], 0, 0, 0);
        __syncthreads();
    }

    int colv[2];
#pragma unroll
    for (int j = 0; j < 2; ++j) colv[j] = n0 + wn * 32 + j * 16 + lm;
    float p0[2], p1[2], p2[2];
#pragma unroll
    for (int j = 0; j < 2; ++j) {
        if (MODE == 0) {
            int bb = m0 >> 9;   // 64-row tiles never straddle a batch
            p0[j] = base[(bb << 9) + colv[j]];
            p1[j] = w_f0[colv[j]];
            p2[j] = w_energy[colv[j]];
        } else {
            p0[j] = bias[colv[j]];
        }
    }
#pragma unroll
    for (int i = 0; i < 2; ++i)
#pragma unroll
        for (int r = 0; r < 4; ++r) {
            int row = m0 + wm * 32 + i * 16 + kq * 4 + r;
            float fv = 0.f, ev = 0.f;
            if (MODE == 0) {
                fv = logf(fmaxf(f0[row], 0.f) + 1e-6f);
                ev = energy[row];
            }
#pragma unroll
            for (int j = 0; j < 2; ++j) {
                float v = acc[i][j][r];
                if (MODE == 0) {
                    v += p0[j] + p1[j] * fv + p2[j] * ev;
                    ((float*)outp)[(size_t)row * NC + colv[j]] = v;
                } else if (MODE == 1) {
                    v += p0[j];
                    v = 0.5f * v * (1.f + erff(v * 0.70710678118654752f));
                    ((ushort*)outp)[(size_t)row * NC + colv[j]] = f2bf(v);
                } else {
                    v += p0[j] + res[(size_t)row * NC + colv[j]];
                    ((float*)outp)[(size_t)row * NC + colv[j]] = v;
                }
            }
        }
}

// ---------------- head (64x64 tiles): filt[m][n] = sum_{k,c} h[b,clamp(t+k-3)][c]*wk[k][n][c] + b_out[n]
__global__ __launch_bounds__(256) void head_mfma(
    const ushort* __restrict__ H, const ushort* __restrict__ WK,
    const float* __restrict__ bias, ushort* __restrict__ out) {
    __shared__ ushort As[64 * 32];
    __shared__ ushort Bs[64 * 32];
    int tid = threadIdx.x;
    int wave = tid >> 6, lane = tid & 63;
    int m0 = blockIdx.x * 64, n0 = blockIdx.y * 64;
    int b = m0 >> 9, tbase = m0 & (NT - 1);
    int srow = tid >> 2, schunk = tid & 3;
    const int ldst = srow * 32 + schunk * 8;
    int lm = lane & 15, kq = lane >> 4;
    int wm = wave & 1, wn = wave >> 1;
    f32x4 acc[2][2];
#pragma unroll
    for (int i = 0; i < 2; ++i)
#pragma unroll
        for (int j = 0; j < 2; ++j) acc[i][j] = (f32x4)0.f;

    for (int k = 0; k < 7; ++k) {
        int t = tbase + srow + k - 3;
        t = min(max(t, 0), NT - 1);
        const ushort* Ag = H + ((size_t)(b << 9) + t) * CI + schunk * 8;
        const ushort* Wg = WK + ((size_t)k * NW + n0 + srow) * CI + schunk * 8;
        for (int c0 = 0; c0 < CI; c0 += 32) {
            ASYNC_COPY16(Ag + c0, &As[ldst]);
            ASYNC_COPY16(Wg + c0, &Bs[ldst]);
            __syncthreads();
            bf16x8 af[2], bf[2];
#pragma unroll
            for (int i = 0; i < 2; ++i)
                af[i] = *(const bf16x8*)&As[(wm * 32 + i * 16 + lm) * 32 + kq * 8];
#pragma unroll
            for (int j = 0; j < 2; ++j)
                bf[j] = *(const bf16x8*)&Bs[(wn * 32 + j * 16 + lm) * 32 + kq * 8];
#pragma unroll
            for (int i = 0; i < 2; ++i)
#pragma unroll
                for (int j = 0; j < 2; ++j)
                    acc[i][j] = __builtin_amdgcn_mfma_f32_16x16x32_bf16(af[i], bf[j], acc[i][j], 0, 0, 0);
            __syncthreads();
        }
    }
#pragma unroll
    for (int i = 0; i < 2; ++i)
#pragma unroll
        for (int j = 0; j < 2; ++j) {
            int col = n0 + wn * 32 + j * 16 + lm;
            float bv = bias[col];
#pragma unroll
            for (int r = 0; r < 4; ++r) {
                int row = m0 + wm * 32 + i * 16 + kq * 4 + r;
                out[(size_t)row * NW + col] = f2bf(acc[i][j][r] + bv);
            }
        }
}

// ---------------- dw conv + LN (wave-per-row, channels strided by 64)
template <bool DW>
__global__ __launch_bounds__(256) void dwln_kernel(const float* __restrict__ X, ushort* __restrict__ H,
                                                   const float* __restrict__ dw_w,
                                                   const float* __restrict__ dw_b,
                                                   const float* __restrict__ g,
                                                   const float* __restrict__ bb) {
    __shared__ float wt[7][512];
    int tid = threadIdx.x;
    if (DW) {
        for (int i = tid; i < 3584; i += 256) {
            int c = i / 7, k = i - c * 7;
            wt[k][c] = dw_w[i];
        }
        __syncthreads();
    }
    int wid = tid >> 6, lane = tid & 63;
    int n = blockIdx.x * 4 + wid;
    int b = n >> 9, t = n & (NT - 1);
    float v[8];
    if (DW) {
#pragma unroll
        for (int i = 0; i < 8; ++i) v[i] = dw_b[lane + 64 * i];
#pragma unroll
        for (int k = 0; k < 7; ++k) {
            int tt = t + k - 3;
            if (tt >= 0 && tt < NT) {
                const float* xr = X + ((size_t)(b << 9) + tt) * CI + lane;
#pragma unroll
                for (int i = 0; i < 8; ++i)
                    v[i] = fmaf(wt[k][lane + 64 * i], xr[64 * i], v[i]);
            }
        }
    } else {
        const float* xr = X + (size_t)n * CI + lane;
#pragma unroll
        for (int i = 0; i < 8; ++i) v[i] = xr[64 * i];
    }
    float s1 = 0.f, s2 = 0.f;
#pragma unroll
    for (int i = 0; i < 8; ++i) { s1 += v[i]; s2 = fmaf(v[i], v[i], s2); }
#pragma unroll
    for (int off = 1; off < 64; off <<= 1) {
        s1 += __shfl_xor(s1, off);
        s2 += __shfl_xor(s2, off);
    }
    float mean = s1 * (1.f / CI);
    float rs = rsqrtf(s2 * (1.f / CI) - mean * mean + 1e-6f);
    ushort* hr = H + (size_t)n * CI + lane;
#pragma unroll
    for (int i = 0; i < 8; ++i) {
        int c = lane + 64 * i;
        hr[64 * i] = f2bf((v[i] - mean) * rs * g[c] + bb[c]);
    }
}

// ---------------- FIR as Toeplitz MFMA GEMM (one block per frame)
__global__ __launch_bounds__(256) void fir_mfma(const float* __restrict__ source,
                                                const ushort* __restrict__ filt,
                                                float* __restrict__ conv) {
    __shared__ ushort sp[3088];         // s at [1040, 2000), zeros elsewhere
    __shared__ ushort Bcm[16][1056];    // Bcm[ul][k]
    int tid = threadIdx.x;
    int bg = blockIdx.x;
    int b = bg >> 9, g = bg & (NT - 1);
    for (int i = tid; i < 520; i += 256) ((unsigned*)sp)[i] = 0;            // [0,1040)
    for (int i = tid; i < 544; i += 256) ((unsigned*)sp)[1000 + i] = 0;     // [2000,3088)
    if (tid < 240) {
        float4 sv = ((const float4*)(source + (size_t)b * LTOT + g * FS))[tid];
        ushort4 o; o.x = f2bf(sv.x); o.y = f2bf(sv.y); o.z = f2bf(sv.z); o.w = f2bf(sv.w);
        *(ushort4*)&sp[1040 + tid * 4] = o;
    }
    const ushort* fr = filt + (size_t)bg * NW;
#pragma unroll
    for (int ul = 0; ul < 16; ++ul)
        for (int k = tid; k < 1056; k += 256) {
            int fi = k - ul - 16;
            Bcm[ul][k] = (fi >= 0 && fi < 1024) ? fr[fi] : (ushort)0;
        }
    __syncthreads();

    int wave = tid >> 6, lane = tid & 63;
    int ln = lane & 15, kq = lane >> 4;
    const ushort* Abase = &sp[16 * ln + 8 * kq];
    const ushort* Bbase = &Bcm[ln][8 * kq];
    int mt0 = wave * 2;
    f32x4 acc0 = (f32x4)0.f, acc1 = (f32x4)0.f;
#pragma unroll 3
    for (int kt = 0; kt < 33; ++kt) {
        bf16x8 bfrag = *(const bf16x8*)(Bbase + 32 * kt);
        bf16x8 a0 = *(const bf16x8*)(Abase + 256 * mt0 + 32 * kt);
        bf16x8 a1 = *(const bf16x8*)(Abase + 256 * (mt0 + 1) + 32 * kt);
        acc0 = __builtin_amdgcn_mfma_f32_16x16x32_bf16(a0, bfrag, acc0, 0, 0, 0);
        acc1 = __builtin_amdgcn_mfma_f32_16x16x32_bf16(a1, bfrag, acc1, 0, 0, 0);
    }
    float* cv = conv + (size_t)bg * CONVW;
#pragma unroll
    for (int r = 0; r < 4; ++r) {
        int m0 = mt0 * 16 + kq * 4 + r;
        cv[16 * m0 + ln] = acc0[r];
        int m1 = m0 + 16;
        if (m1 < 124) cv[16 * m1 + ln] = acc1[r];
    }
}

// ---------------- overlap-add fold
__global__ void fold_kernel(const float* __restrict__ conv, float* __restrict__ out) {
    int b = blockIdx.y;
    int t = blockIdx.x * blockDim.x + threadIdx.x;
    float sum = 0.f;
    int G = (t - 1) / 960;
#pragma unroll
    for (int r = 0; r < 3; ++r) {
        int g = G - r;
        if (g >= 0) {
            int u = t - 960 * g;
            if (u < CONVW) sum += conv[((size_t)(b * NT + g)) * CONVW + u];
        }
    }
    out[(size_t)b * LTOT + t] = sum;
}

extern "C" void kernel_launch(void* const* d_in, const int* in_sizes, int n_in,
                              void* d_out, int out_size, void* d_ws, size_t ws_size,
                              hipStream_t stream) {
    const float* content  = (const float*)d_in[0];
    const float* f0       = (const float*)d_in[1];
    const float* energy   = (const float*)d_in[2];
    const float* spk      = (const float*)d_in[3];
    const float* source   = (const float*)d_in[4];
    const float* w_content= (const float*)d_in[5];
    const float* b_content= (const float*)d_in[6];
    const float* w_spk    = (const float*)d_in[7];
    const float* b_spk    = (const float*)d_in[8];
    const float* w_f0     = (const float*)d_in[9];
    const float* b_f0     = (const float*)d_in[10];
    const float* w_energy = (const float*)d_in[11];
    const float* b_energy = (const float*)d_in[12];
    const float* dw_w     = (const float*)d_in[13];
    const float* dw_b     = (const float*)d_in[14];
    const float* ln_g     = (const float*)d_in[15];
    const float* ln_b     = (const float*)d_in[16];
    const float* pw1_w    = (const float*)d_in[17];
    const float* pw1_b    = (const float*)d_in[18];
    const float* pw2_w    = (const float*)d_in[19];
    const float* pw2_b    = (const float*)d_in[20];
    const float* out_ln_g = (const float*)d_in[21];
    const float* out_ln_b = (const float*)d_in[22];
    const float* w_out    = (const float*)d_in[23];
    const float* b_out    = (const float*)d_in[24];
    float* out = (float*)d_out;

    float* ws = (float*)d_ws;
    // layout (float offsets)
    float*  x     = ws;                              // 2,097,152 f
    float*  base  = ws + 2097152;                    // 4,096 f
    ushort* ctb   = (ushort*)(ws + 2101248);         // 786,432 bf16 (393,216 f)
    ushort* wcb   = (ushort*)(ws + 2494464);         // 98,304 bf16 (49,152 f)
    ushort* filtb = (ushort*)(ws + 2543616);         // 4,194,304 bf16 (2,097,152 f)
    ushort* h     = (ushort*)(ws + 4640768);         // 2,097,152 bf16 (1,048,576 f)
    ushort* pw1w  = (ushort*)(ws + 5689344);         // 4,718,592 bf16 (2,359,296 f)
    ushort* pw2w  = (ushort*)(ws + 8048640);         // 4,718,592 bf16 (2,359,296 f)
    ushort* wk    = (ushort*)(ws + 10407936);        // 3,670,016 bf16 (1,835,008 f)
    ushort* hmid  = (ushort*)(ws + 12242944);        // 6,291,456 bf16 (3,145,728 f)
    float*  conv  = ws + 5689344;                    // 8,126,464 f — overlays pw/wk/hmid (dead by fir)
    // total 15,388,672 f = 61.6 MB

    cvt_bf16<<<4608, 256, 0, stream>>>(pw1_w, pw1w, 1179648);
    cvt_bf16<<<4608, 256, 0, stream>>>(pw2_w, pw2w, 1179648);
    cvt_bf16<<<96, 256, 0, stream>>>(w_content, wcb, 24576);
    cvt_wout<<<NW, 256, 0, stream>>>(w_out, wk);
    spkbase_kernel<<<NB, 256, 0, stream>>>(spk, w_spk, b_spk, b_content, b_f0, b_energy, base);
    transpose_content<<<dim3(16, 6, NB), dim3(32, 8), 0, stream>>>(content, ctb);

    // trunk (bf16 MFMA, MODE 0): x = ctb @ wcb^T + base + w_f0*logf0 + w_energy*energy
    gemm_mfma64<0><<<dim3(NROWS / 64, CI / 64), 256, 0, stream>>>(
        ctb, wcb, nullptr, x, nullptr, CCON, CI, f0, energy, w_f0, w_energy, base);

    for (int i = 0; i < 6; ++i) {
        dwln_kernel<true><<<NROWS / 4, 256, 0, stream>>>(x, h, dw_w + i * CI * 7, dw_b + i * CI,
                                                         ln_g + i * CI, ln_b + i * CI);
        gemm_mfma64<1><<<dim3(NROWS / 64, DM / 64), 256, 0, stream>>>(
            h, pw1w + (size_t)i * DM * CI, pw1_b + i * DM, hmid, nullptr, CI, DM,
            nullptr, nullptr, nullptr, nullptr, nullptr);
        gemm_mfma64<2><<<dim3(NROWS / 64, CI / 64), 256, 0, stream>>>(
            hmid, pw2w + (size_t)i * CI * DM, pw2_b + i * CI, x, x, DM, CI,
            nullptr, nullptr, nullptr, nullptr, nullptr);
    }

    dwln_kernel<false><<<NROWS / 4, 256, 0, stream>>>(x, h, nullptr, nullptr, out_ln_g, out_ln_b);
    head_mfma<<<dim3(NROWS / 64, NW / 64), 256, 0, stream>>>(h, wk, b_out, filtb);
    fir_mfma<<<NROWS, 256, 0, stream>>>(source, filtb, conv);
    fold_kernel<<<dim3(LTOT / 256, NB), 256, 0, stream>>>(conv, out);
}

// Round 7
// 552.189 us; speedup vs baseline: 1.9241x; 1.0780x over previous
//
#include <hip/hip_runtime.h>
#include <math.h>

// Problem constants
#define NB 8
#define NT 512           // N_FRAMES
#define NROWS 4096       // NB*NT
#define CI 512           // C_INT
#define DM 1536          // D_MLP
#define CCON 192
#define CSPK 256
#define NW 1024          // N_WINDOW
#define FS 960           // FRAME_SIZE
#define LTOT 491520      // NT*FS
#define CONVW 1984       // FS+NW

typedef __bf16 bf16x8 __attribute__((ext_vector_type(8)));
typedef float f32x4 __attribute__((ext_vector_type(4)));
typedef unsigned short ushort;
typedef unsigned int uint;

__device__ __forceinline__ ushort f2bf(float x) {
    union { float f; unsigned u; } v; v.f = x;
    unsigned r = v.u + 0x7fff + ((v.u >> 16) & 1);
    return (ushort)(r >> 16);
}

#define ASYNC_COPY16(g, l) __builtin_amdgcn_global_load_lds( \
    (const __attribute__((address_space(1))) void*)(g), \
    (__attribute__((address_space(3))) void*)(l), 16, 0, 0)

// ---------------- weight fp32 -> bf16 (elementwise, 4/thread)
__global__ void cvt_bf16(const float* __restrict__ in, ushort* __restrict__ out, int n4) {
    int i = blockIdx.x * 256 + threadIdx.x;
    if (i < n4) {
        float4 v = ((const float4*)in)[i];
        ushort4 o; o.x = f2bf(v.x); o.y = f2bf(v.y); o.z = f2bf(v.z); o.w = f2bf(v.w);
        ((ushort4*)out)[i] = o;
    }
}

// ---------------- w_out (NW, CI, 7) -> wk[k][n][c] bf16
__global__ void cvt_wout(const float* __restrict__ w, ushort* __restrict__ wk) {
    int n = blockIdx.x, tid = threadIdx.x;
    __shared__ ushort s[7][512];
#pragma unroll
    for (int h = 0; h < 2; ++h) {
        int c = tid + h * 256;
        const float* p = w + ((size_t)n * 512 + c) * 7;
#pragma unroll
        for (int k = 0; k < 7; ++k) s[k][c] = f2bf(p[k]);
    }
    __syncthreads();
#pragma unroll
    for (int k = 0; k < 7; ++k)
#pragma unroll
        for (int h = 0; h < 2; ++h) {
            int c = tid + h * 256;
            wk[((size_t)k * NW + n) * CI + c] = s[k][c];
        }
}

// ---------------- spk base
__global__ void spkbase_kernel(const float* __restrict__ spk, const float* __restrict__ w_spk,
                               const float* __restrict__ b_spk, const float* __restrict__ b_content,
                               const float* __restrict__ b_f0, const float* __restrict__ b_energy,
                               float* __restrict__ base) {
    int b = blockIdx.x, tid = threadIdx.x;
    __shared__ float s[CSPK];
    if (tid < CSPK) s[tid] = spk[b * CSPK + tid];
    __syncthreads();
    for (int o = tid; o < CI; o += 256) {
        float acc = 0.f;
        for (int c = 0; c < CSPK; ++c) acc = fmaf(w_spk[o * CSPK + c], s[c], acc);
        base[b * CI + o] = acc + b_spk[o] + b_content[o] + b_f0[o] + b_energy[o];
    }
}

// ---------------- content transpose: (B, 192, T) -> ct[(b*T+t)][c] (bf16)
__global__ void transpose_content(const float* __restrict__ content, ushort* __restrict__ ct) {
    __shared__ float tile[32][33];
    int b = blockIdx.z, c0 = blockIdx.y * 32, t0 = blockIdx.x * 32;
    int x = threadIdx.x, y = threadIdx.y;
#pragma unroll
    for (int i = 0; i < 32; i += 8)
        tile[y + i][x] = content[((size_t)b * CCON + c0 + y + i) * NT + t0 + x];
    __syncthreads();
#pragma unroll
    for (int i = 0; i < 32; i += 8)
        ct[((size_t)b * NT + t0 + y + i) * CCON + c0 + x] = f2bf(tile[x][y + i]);
}

// ---------------- 64x64 bf16 MFMA GEMM, XOR-swizzled LDS chunks (kills 8-way frag conflicts)
// LDS chunk position c of row r holds global K-chunk (c ^ ((r>>1)&3)).
// MODE 0: trunk epilogue, fp32 out. MODE 1: +bias,gelu, bf16 out. MODE 2: +bias+res, fp32 out.
template <int MODE>
__global__ __launch_bounds__(256) void gemm_mfma64(
    const ushort* __restrict__ A, const ushort* __restrict__ W,
    const float* __restrict__ bias, void* __restrict__ outp,
    const float* __restrict__ res, int K, int NC,
    const float* __restrict__ f0, const float* __restrict__ energy,
    const float* __restrict__ w_f0, const float* __restrict__ w_energy,
    const float* __restrict__ base) {
    __shared__ ushort As[64 * 32];
    __shared__ ushort Bs[64 * 32];
    int tid = threadIdx.x;
    int wave = tid >> 6, lane = tid & 63;
    int m0 = blockIdx.x * 64, n0 = blockIdx.y * 64;
    int srow = tid >> 2, schunk = tid & 3;
    int sg = schunk ^ ((srow >> 1) & 3);            // swizzled global chunk
    const ushort* Ag = A + (size_t)(m0 + srow) * K + sg * 8;
    const ushort* Wg = W + (size_t)(n0 + srow) * K + sg * 8;
    const int ldst = srow * 32 + schunk * 8;
    int lm = lane & 15, kq = lane >> 4;
    int csw = (kq ^ ((lm >> 1) & 3)) * 8;           // swizzled LDS chunk for frag reads
    int wm = wave & 1, wn = wave >> 1;
    f32x4 acc[2][2];
#pragma unroll
    for (int i = 0; i < 2; ++i)
#pragma unroll
        for (int j = 0; j < 2; ++j) acc[i][j] = (f32x4)0.f;

    for (int k0 = 0; k0 < K; k0 += 32) {
        ASYNC_COPY16(Ag + k0, &As[ldst]);
        ASYNC_COPY16(Wg + k0, &Bs[ldst]);
        __syncthreads();
        bf16x8 af[2], bf[2];
#pragma unroll
        for (int i = 0; i < 2; ++i)
            af[i] = *(const bf16x8*)&As[(wm * 32 + i * 16 + lm) * 32 + csw];
#pragma unroll
        for (int j = 0; j < 2; ++j)
            bf[j] = *(const bf16x8*)&Bs[(wn * 32 + j * 16 + lm) * 32 + csw];
#pragma unroll
        for (int i = 0; i < 2; ++i)
#pragma unroll
            for (int j = 0; j < 2; ++j)
                acc[i][j] = __builtin_amdgcn_mfma_f32_16x16x32_bf16(af[i], bf[j], acc[i][j], 0, 0, 0);
        __syncthreads();
    }

    int colv[2];
#pragma unroll
    for (int j = 0; j < 2; ++j) colv[j] = n0 + wn * 32 + j * 16 + lm;
    float p0[2], p1[2], p2[2];
#pragma unroll
    for (int j = 0; j < 2; ++j) {
        if (MODE == 0) {
            int bb = m0 >> 9;
            p0[j] = base[(bb << 9) + colv[j]];
            p1[j] = w_f0[colv[j]];
            p2[j] = w_energy[colv[j]];
        } else {
            p0[j] = bias[colv[j]];
        }
    }
#pragma unroll
    for (int i = 0; i < 2; ++i)
#pragma unroll
        for (int r = 0; r < 4; ++r) {
            int row = m0 + wm * 32 + i * 16 + kq * 4 + r;
            float fv = 0.f, ev = 0.f;
            if (MODE == 0) {
                fv = logf(fmaxf(f0[row], 0.f) + 1e-6f);
                ev = energy[row];
            }
#pragma unroll
            for (int j = 0; j < 2; ++j) {
                float v = acc[i][j][r];
                if (MODE == 0) {
                    v += p0[j] + p1[j] * fv + p2[j] * ev;
                    ((float*)outp)[(size_t)row * NC + colv[j]] = v;
                } else if (MODE == 1) {
                    v += p0[j];
                    v = 0.5f * v * (1.f + erff(v * 0.70710678118654752f));
                    ((ushort*)outp)[(size_t)row * NC + colv[j]] = f2bf(v);
                } else {
                    v += p0[j] + res[(size_t)row * NC + colv[j]];
                    ((float*)outp)[(size_t)row * NC + colv[j]] = v;
                }
            }
        }
}

// ---------------- head (64x64 tiles, swizzled): filt[m][n] = sum_{k,c} h[b,clamp(t+k-3)][c]*wk[k][n][c] + b_out[n]
__global__ __launch_bounds__(256) void head_mfma(
    const ushort* __restrict__ H, const ushort* __restrict__ WK,
    const float* __restrict__ bias, ushort* __restrict__ out) {
    __shared__ ushort As[64 * 32];
    __shared__ ushort Bs[64 * 32];
    int tid = threadIdx.x;
    int wave = tid >> 6, lane = tid & 63;
    int m0 = blockIdx.x * 64, n0 = blockIdx.y * 64;
    int b = m0 >> 9, tbase = m0 & (NT - 1);
    int srow = tid >> 2, schunk = tid & 3;
    int sg = schunk ^ ((srow >> 1) & 3);
    const int ldst = srow * 32 + schunk * 8;
    int lm = lane & 15, kq = lane >> 4;
    int csw = (kq ^ ((lm >> 1) & 3)) * 8;
    int wm = wave & 1, wn = wave >> 1;
    f32x4 acc[2][2];
#pragma unroll
    for (int i = 0; i < 2; ++i)
#pragma unroll
        for (int j = 0; j < 2; ++j) acc[i][j] = (f32x4)0.f;

    for (int k = 0; k < 7; ++k) {
        int t = tbase + srow + k - 3;
        t = min(max(t, 0), NT - 1);
        const ushort* Ag = H + ((size_t)(b << 9) + t) * CI + sg * 8;
        const ushort* Wg = WK + ((size_t)k * NW + n0 + srow) * CI + sg * 8;
        for (int c0 = 0; c0 < CI; c0 += 32) {
            ASYNC_COPY16(Ag + c0, &As[ldst]);
            ASYNC_COPY16(Wg + c0, &Bs[ldst]);
            __syncthreads();
            bf16x8 af[2], bf[2];
#pragma unroll
            for (int i = 0; i < 2; ++i)
                af[i] = *(const bf16x8*)&As[(wm * 32 + i * 16 + lm) * 32 + csw];
#pragma unroll
            for (int j = 0; j < 2; ++j)
                bf[j] = *(const bf16x8*)&Bs[(wn * 32 + j * 16 + lm) * 32 + csw];
#pragma unroll
            for (int i = 0; i < 2; ++i)
#pragma unroll
                for (int j = 0; j < 2; ++j)
                    acc[i][j] = __builtin_amdgcn_mfma_f32_16x16x32_bf16(af[i], bf[j], acc[i][j], 0, 0, 0);
            __syncthreads();
        }
    }
#pragma unroll
    for (int i = 0; i < 2; ++i)
#pragma unroll
        for (int j = 0; j < 2; ++j) {
            int col = n0 + wn * 32 + j * 16 + lm;
            float bv = bias[col];
#pragma unroll
            for (int r = 0; r < 4; ++r) {
                int row = m0 + wm * 32 + i * 16 + kq * 4 + r;
                out[(size_t)row * NW + col] = f2bf(acc[i][j][r] + bv);
            }
        }
}

// ---------------- dw conv + LN (wave-per-row, channels strided by 64)
template <bool DW>
__global__ __launch_bounds__(256) void dwln_kernel(const float* __restrict__ X, ushort* __restrict__ H,
                                                   const float* __restrict__ dw_w,
                                                   const float* __restrict__ dw_b,
                                                   const float* __restrict__ g,
                                                   const float* __restrict__ bb) {
    __shared__ float wt[7][512];
    int tid = threadIdx.x;
    if (DW) {
        for (int i = tid; i < 3584; i += 256) {
            int c = i / 7, k = i - c * 7;
            wt[k][c] = dw_w[i];
        }
        __syncthreads();
    }
    int wid = tid >> 6, lane = tid & 63;
    int n = blockIdx.x * 4 + wid;
    int b = n >> 9, t = n & (NT - 1);
    float v[8];
    if (DW) {
#pragma unroll
        for (int i = 0; i < 8; ++i) v[i] = dw_b[lane + 64 * i];
#pragma unroll
        for (int k = 0; k < 7; ++k) {
            int tt = t + k - 3;
            if (tt >= 0 && tt < NT) {
                const float* xr = X + ((size_t)(b << 9) + tt) * CI + lane;
#pragma unroll
                for (int i = 0; i < 8; ++i)
                    v[i] = fmaf(wt[k][lane + 64 * i], xr[64 * i], v[i]);
            }
        }
    } else {
        const float* xr = X + (size_t)n * CI + lane;
#pragma unroll
        for (int i = 0; i < 8; ++i) v[i] = xr[64 * i];
    }
    float s1 = 0.f, s2 = 0.f;
#pragma unroll
    for (int i = 0; i < 8; ++i) { s1 += v[i]; s2 = fmaf(v[i], v[i], s2); }
#pragma unroll
    for (int off = 1; off < 64; off <<= 1) {
        s1 += __shfl_xor(s1, off);
        s2 += __shfl_xor(s2, off);
    }
    float mean = s1 * (1.f / CI);
    float rs = rsqrtf(s2 * (1.f / CI) - mean * mean + 1e-6f);
    ushort* hr = H + (size_t)n * CI + lane;
#pragma unroll
    for (int i = 0; i < 8; ++i) {
        int c = lane + 64 * i;
        hr[64 * i] = f2bf((v[i] - mean) * rs * g[c] + bb[c]);
    }
}

// ---------------- FIR as Toeplitz MFMA GEMM (one block per frame)
// Bcm row stride padded 1056->1064 el (532 words, !=0 mod 32: 8-way -> free 2-way).
// Bcm built via dword shifts from a guarded dword staging of the filter.
__global__ __launch_bounds__(256) void fir_mfma(const float* __restrict__ source,
                                                const ushort* __restrict__ filt,
                                                float* __restrict__ conv) {
    __shared__ ushort sp[3088];          // Toeplitz src: s at el [1040,2000), zeros elsewhere
    __shared__ uint Bcm32[16 * 532];     // Bcm[ul][k]: row stride 532 dwords (1064 el)
    uint* sp32 = (uint*)sp;
    uint* G = sp32 + 1004;               // 536-dword guarded filter staging (dies before compute)
    int tid = threadIdx.x;
    int bg = blockIdx.x;
    int b = bg >> 9, g = bg & (NT - 1);

    // phase 1: zero sp head, stage guarded filter dwords, stage source (all disjoint)
    for (int i = tid; i < 520; i += 256) sp32[i] = 0;                    // sp el [0,1040)
    if (tid < 16) G[tid] = 0;
    else if (tid < 24) G[512 + tid] = 0;                                 // G[528..535]
    const uint* fr32 = (const uint*)(filt + (size_t)bg * NW);            // 512 dwords
    G[16 + tid] = fr32[tid];
    G[272 + tid] = fr32[256 + tid];
    if (tid < 240) {
        float4 sv = ((const float4*)(source + (size_t)b * LTOT + g * FS))[tid];
        ushort4 o; o.x = f2bf(sv.x); o.y = f2bf(sv.y); o.z = f2bf(sv.z); o.w = f2bf(sv.w);
        *(ushort4*)&sp[1040 + tid * 4] = o;
    }
    __syncthreads();

    // phase 2: build 16 shifted filter rows from dword window
    // Bcm[ul][2d..2d+1] = fpad[2d-ul], fpad[2d+1-ul];  fpad dword j = G[16+j-8] => window G[d..d+8]
#pragma unroll 1
    for (int p = 0; p < 3; ++p) {
        int d = tid + p * 256;
        if (d < 528) {
            uint w[9];
#pragma unroll
            for (int q = 0; q < 9; ++q) w[q] = G[d + q];
#pragma unroll
            for (int ul = 0; ul < 16; ++ul) {
                uint val;
                if ((ul & 1) == 0) val = w[8 - (ul >> 1)];
                else {
                    int a = 8 - ((ul + 1) >> 1);
                    val = (w[a] >> 16) | (w[a + 1] << 16);
                }
                Bcm32[ul * 532 + d] = val;
            }
        }
    }
    __syncthreads();

    // phase 3: zero sp tail (G region now dead)
    for (int i = 1000 + tid; i < 1544; i += 256) sp32[i] = 0;
    __syncthreads();

    int wave = tid >> 6, lane = tid & 63;
    int ln = lane & 15, kq = lane >> 4;
    const ushort* Abase = &sp[16 * ln + 8 * kq];
    const ushort* Bbase = (const ushort*)&Bcm32[ln * 532] + 8 * kq;
    int mt0 = wave * 2;
    f32x4 acc0 = (f32x4)0.f, acc1 = (f32x4)0.f;
#pragma unroll 3
    for (int kt = 0; kt < 33; ++kt) {
        bf16x8 bfrag = *(const bf16x8*)(Bbase + 32 * kt);
        bf16x8 a0 = *(const bf16x8*)(Abase + 256 * mt0 + 32 * kt);
        bf16x8 a1 = *(const bf16x8*)(Abase + 256 * (mt0 + 1) + 32 * kt);
        acc0 = __builtin_amdgcn_mfma_f32_16x16x32_bf16(a0, bfrag, acc0, 0, 0, 0);
        acc1 = __builtin_amdgcn_mfma_f32_16x16x32_bf16(a1, bfrag, acc1, 0, 0, 0);
    }
    float* cv = conv + (size_t)bg * CONVW;
#pragma unroll
    for (int r = 0; r < 4; ++r) {
        int m0 = mt0 * 16 + kq * 4 + r;
        cv[16 * m0 + ln] = acc0[r];
        int m1 = m0 + 16;
        if (m1 < 124) cv[16 * m1 + ln] = acc1[r];
    }
}

// ---------------- overlap-add fold
__global__ void fold_kernel(const float* __restrict__ conv, float* __restrict__ out) {
    int b = blockIdx.y;
    int t = blockIdx.x * blockDim.x + threadIdx.x;
    float sum = 0.f;
    int G = (t - 1) / 960;
#pragma unroll
    for (int r = 0; r < 3; ++r) {
        int g = G - r;
        if (g >= 0) {
            int u = t - 960 * g;
            if (u < CONVW) sum += conv[((size_t)(b * NT + g)) * CONVW + u];
        }
    }
    out[(size_t)b * LTOT + t] = sum;
}

extern "C" void kernel_launch(void* const* d_in, const int* in_sizes, int n_in,
                              void* d_out, int out_size, void* d_ws, size_t ws_size,
                              hipStream_t stream) {
    const float* content  = (const float*)d_in[0];
    const float* f0       = (const float*)d_in[1];
    const float* energy   = (const float*)d_in[2];
    const float* spk      = (const float*)d_in[3];
    const float* source   = (const float*)d_in[4];
    const float* w_content= (const float*)d_in[5];
    const float* b_content= (const float*)d_in[6];
    const float* w_spk    = (const float*)d_in[7];
    const float* b_spk    = (const float*)d_in[8];
    const float* w_f0     = (const float*)d_in[9];
    const float* b_f0     = (const float*)d_in[10];
    const float* w_energy = (const float*)d_in[11];
    const float* b_energy = (const float*)d_in[12];
    const float* dw_w     = (const float*)d_in[13];
    const float* dw_b     = (const float*)d_in[14];
    const float* ln_g     = (const float*)d_in[15];
    const float* ln_b     = (const float*)d_in[16];
    const float* pw1_w    = (const float*)d_in[17];
    const float* pw1_b    = (const float*)d_in[18];
    const float* pw2_w    = (const float*)d_in[19];
    const float* pw2_b    = (const float*)d_in[20];
    const float* out_ln_g = (const float*)d_in[21];
    const float* out_ln_b = (const float*)d_in[22];
    const float* w_out    = (const float*)d_in[23];
    const float* b_out    = (const float*)d_in[24];
    float* out = (float*)d_out;

    float* ws = (float*)d_ws;
    // layout (float offsets)
    float*  x     = ws;                              // 2,097,152 f
    float*  base  = ws + 2097152;                    // 4,096 f
    ushort* ctb   = (ushort*)(ws + 2101248);         // 786,432 bf16
    ushort* wcb   = (ushort*)(ws + 2494464);         // 98,304 bf16
    ushort* filtb = (ushort*)(ws + 2543616);         // 4,194,304 bf16
    ushort* h     = (ushort*)(ws + 4640768);         // 2,097,152 bf16
    ushort* pw1w  = (ushort*)(ws + 5689344);         // 4,718,592 bf16
    ushort* pw2w  = (ushort*)(ws + 8048640);         // 4,718,592 bf16
    ushort* wk    = (ushort*)(ws + 10407936);        // 3,670,016 bf16
    ushort* hmid  = (ushort*)(ws + 12242944);        // 6,291,456 bf16
    float*  conv  = ws + 5689344;                    // 8,126,464 f — overlays pw/wk/hmid (dead by fir)

    cvt_bf16<<<4608, 256, 0, stream>>>(pw1_w, pw1w, 1179648);
    cvt_bf16<<<4608, 256, 0, stream>>>(pw2_w, pw2w, 1179648);
    cvt_bf16<<<96, 256, 0, stream>>>(w_content, wcb, 24576);
    cvt_wout<<<NW, 256, 0, stream>>>(w_out, wk);
    spkbase_kernel<<<NB, 256, 0, stream>>>(spk, w_spk, b_spk, b_content, b_f0, b_energy, base);
    transpose_content<<<dim3(16, 6, NB), dim3(32, 8), 0, stream>>>(content, ctb);

    // trunk (bf16 MFMA, MODE 0)
    gemm_mfma64<0><<<dim3(NROWS / 64, CI / 64), 256, 0, stream>>>(
        ctb, wcb, nullptr, x, nullptr, CCON, CI, f0, energy, w_f0, w_energy, base);

    for (int i = 0; i < 6; ++i) {
        dwln_kernel<true><<<NROWS / 4, 256, 0, stream>>>(x, h, dw_w + i * CI * 7, dw_b + i * CI,
                                                         ln_g + i * CI, ln_b + i * CI);
        gemm_mfma64<1><<<dim3(NROWS / 64, DM / 64), 256, 0, stream>>>(
            h, pw1w + (size_t)i * DM * CI, pw1_b + i * DM, hmid, nullptr, CI, DM,
            nullptr, nullptr, nullptr, nullptr, nullptr);
        gemm_mfma64<2><<<dim3(NROWS / 64, CI / 64), 256, 0, stream>>>(
            hmid, pw2w + (size_t)i * CI * DM, pw2_b + i * CI, x, x, DM, CI,
            nullptr, nullptr, nullptr, nullptr, nullptr);
    }

    dwln_kernel<false><<<NROWS / 4, 256, 0, stream>>>(x, h, nullptr, nullptr, out_ln_g, out_ln_b);
    head_mfma<<<dim3(NROWS / 64, NW / 64), 256, 0, stream>>>(h, wk, b_out, filtb);
    fir_mfma<<<NROWS, 256, 0, stream>>>(source, filtb, conv);
    fold_kernel<<<dim3(LTOT / 256, NB), 256, 0, stream>>>(conv, out);
}